// Round 11
// baseline (636.749 us; speedup 1.0000x reference)
//
#include <hip/hip_runtime.h>

typedef unsigned short u16;
typedef unsigned int   u32;
typedef __attribute__((ext_vector_type(8))) _Float16 f16x8;
typedef __attribute__((ext_vector_type(2))) float f32x2;
typedef __attribute__((ext_vector_type(4))) float f32x4;
typedef __attribute__((ext_vector_type(4))) unsigned int u32x4;

constexpr int B_  = 4;
constexpr int C0  = 128;
constexpr int C1  = 32;
constexpr int H_  = 96;
constexpr int W_  = 96;
constexpr int HW  = H_ * W_;        // 9216
constexpr int PT  = 64;
constexpr int TPB = HW / PT;        // 144
constexpr int NTILE = B_ * TPB;     // 576

__device__ inline u16 f2h(float f) {
    _Float16 h = (_Float16)f;
    return __builtin_bit_cast(u16, h);
}

// ---------------------------------------------------------------------------
// Weight prep (unchanged)
__global__ __launch_bounds__(256) void k_prep(
    const float* __restrict__ w_off,
    const float* __restrict__ wd1,  const float* __restrict__ wd2,
    const float* __restrict__ s1c0, const float* __restrict__ s1h0,
    const float* __restrict__ s2c0, const float* __restrict__ s2h0,
    const float* __restrict__ s1c1, const float* __restrict__ s1h1,
    const float* __restrict__ s2c1, const float* __restrict__ s2h1,
    float* __restrict__ wofft, u16* __restrict__ wdhi, u16* __restrict__ wdlo,
    u16* __restrict__ w0h,     u16* __restrict__ w1h)
{
    int t = blockIdx.x * 256 + threadIdx.x;
    if (t < C0 * 18 * 9) {
        int c = t / 162, r = t % 162, o = r / 9, tap = r % 9;
        wofft[t] = w_off[(o * C0 + c) * 9 + tap];
    }
    if (t < 2 * 9 * C0 * C0) {
        int d = t / (9 * C0 * C0), r = t % (9 * C0 * C0);
        int k = r / (C0 * C0), r2 = r % (C0 * C0), o = r2 / C0, c = r2 % C0;
        const float* wsrc = d ? wd2 : wd1;
        float wv = wsrc[(o * C0 + c) * 9 + k];
        _Float16 hi = (_Float16)wv;
        float rr = wv - (float)hi;
        wdhi[t] = __builtin_bit_cast(u16, hi);
        wdlo[t] = f2h(rr);
    }
    if (t < 4 * C0 * C1) {
        int m = t / (C0 * C1), i = t % (C0 * C1);
        const float* s = (m == 0) ? s1c0 : (m == 1) ? s1h0 : (m == 2) ? s2c0 : s2h0;
        w0h[t] = f2h(s[i]);
    }
    if (t < 4 * C0 * C0) {
        int m = t / (C0 * C0), i = t % (C0 * C0);
        const float* s = (m == 0) ? s1c1 : (m == 1) ? s1h1 : (m == 2) ? s2c1 : s2h1;
        w1h[t] = f2h(s[i]);
    }
}

// ---------------------------------------------------------------------------
// Offset conv: 3x3, 128 -> 18 (f32, round-1 proven)
__global__ __launch_bounds__(256) void k_conv_off(
    const float* __restrict__ x0, const float* __restrict__ wofft,
    const float* __restrict__ boff, float* __restrict__ off)
{
    int bx = blockIdx.x;
    int b  = bx / TPB;
    int p0 = (bx % TPB) * PT;
    int tid = threadIdx.x;
    int p   = tid & 63;
    int cq  = __builtin_amdgcn_readfirstlane(tid >> 6);
    int pos = p0 + p;
    int h = pos / W_, w = pos % W_;

    float acc[18];
#pragma unroll
    for (int o = 0; o < 18; ++o) acc[o] = 0.f;

    for (int cc = 0; cc < 32; ++cc) {
        int c = cq * 32 + cc;
        const float* xb = x0 + ((size_t)(b * C0 + c)) * HW;
        float v[9];
#pragma unroll
        for (int t = 0; t < 9; ++t) {
            int dy = t / 3 - 1, dx = t % 3 - 1;
            int hy = h + dy, wx = w + dx;
            bool ok = (hy >= 0) & (hy < H_) & (wx >= 0) & (wx < W_);
            v[t] = ok ? xb[hy * W_ + wx] : 0.f;
        }
        const float* wr = wofft + c * 162;
#pragma unroll
        for (int o = 0; o < 18; ++o)
#pragma unroll
            for (int t = 0; t < 9; ++t)
                acc[o] = fmaf(wr[o * 9 + t], v[t], acc[o]);
    }

    __shared__ float red[4][18][PT];
#pragma unroll
    for (int o = 0; o < 18; ++o) red[cq][o][p] = acc[o];
    __syncthreads();
    for (int idx = tid; idx < 18 * PT; idx += 256) {
        int o = idx / PT, pp = idx % PT;
        float s = red[0][o][pp] + red[1][o][pp] + red[2][o][pp] + red[3][o][pp]
                + boff[o];
        off[((size_t)(b * 18 + o)) * HW + p0 + pp] = s;
    }
}

// ---------------------------------------------------------------------------
// Fused SFT via MFMA.  v2: no output LDS staging (direct global writes),
// LDS 37 KB -> 3 blocks/CU co-resident.
template <int XSRC>
__global__ __launch_bounds__(512, 6) void k_sft_mma(
    const float* __restrict__ xf,     // XSRC==0
    const float* __restrict__ xT,     // XSRC==1
    const float* __restrict__ x1,
    const u16* __restrict__ w0s, const u16* __restrict__ w0h,   // [128 hid][32 ch]
    const u16* __restrict__ w1s, const u16* __restrict__ w1h,   // [128 out][128 hid]
    const float* __restrict__ b0s, const float* __restrict__ b0h,
    const float* __restrict__ b1s, const float* __restrict__ b1h,
    float* __restrict__ outT)         // [B,HW,128]
{
    __shared__ __align__(16) u16 x1t[64 * 32];
    __shared__ __align__(16) u16 hidt[2][64 * 128];

    int bx = blockIdx.x, b = bx / TPB, p0 = (bx % TPB) * PT;
    int tid = threadIdx.x, l = tid & 63;
    int w = __builtin_amdgcn_readfirstlane(tid >> 6);
    f32x4 zz = {0.f, 0.f, 0.f, 0.f};

    for (int i = tid; i < C1 * PT; i += 512) {
        int ch = i >> 6, pos = i & 63;
        float v = x1[((size_t)(b * C1 + ch)) * HW + p0 + pos];
        x1t[pos * 32 + (ch ^ ((pos & 3) << 3))] = f2h(v);
    }
    __syncthreads();

    {   // hidden GEMM (K=32)
        int mt = w & 3, br = w >> 2;
        int pos = mt * 16 + (l & 15);
        int koff = (l >> 4) * 8;
        f16x8 a = *(const f16x8*)&x1t[pos * 32 + (koff ^ ((pos & 3) << 3))];
        const u16* w0 = br ? w0h : w0s;
        const float* bb = br ? b0h : b0s;
        u16* hrow = hidt[br];
#pragma unroll
        for (int nt = 0; nt < 8; ++nt) {
            int n = nt * 16 + (l & 15);
            f16x8 bfr = *(const f16x8*)&w0[n * 32 + koff];
            f32x4 h = __builtin_amdgcn_mfma_f32_16x16x32_f16(a, bfr, zz, 0, 0, 0);
            float bv = bb[n];
#pragma unroll
            for (int r = 0; r < 4; ++r) {
                float hv = h[r] + bv;
                hv = hv > 0.f ? hv : 0.1f * hv;
                int prow = mt * 16 + (l >> 4) * 4 + r;
                hrow[prow * 128 + (n ^ ((prow & 7) << 3))] = f2h(hv);
            }
        }
    }
    __syncthreads();

    f32x4 accS[4], accH[4];
#pragma unroll
    for (int nt = 0; nt < 4; ++nt) { accS[nt] = zz; accH[nt] = zz; }
    int mt = w & 3, nh = w >> 2;
    int pos = mt * 16 + (l & 15);
#pragma unroll
    for (int ks = 0; ks < 4; ++ks) {
        int kb = ks * 32 + (l >> 4) * 8;
        f16x8 aS = *(const f16x8*)&hidt[0][pos * 128 + (kb ^ ((pos & 7) << 3))];
        f16x8 aH = *(const f16x8*)&hidt[1][pos * 128 + (kb ^ ((pos & 7) << 3))];
#pragma unroll
        for (int nt = 0; nt < 4; ++nt) {
            int n = nh * 64 + nt * 16 + (l & 15);
            f16x8 bS = *(const f16x8*)&w1s[n * 128 + kb];
            f16x8 bH = *(const f16x8*)&w1h[n * 128 + kb];
            accS[nt] = __builtin_amdgcn_mfma_f32_16x16x32_f16(aS, bS, accS[nt], 0, 0, 0);
            accH[nt] = __builtin_amdgcn_mfma_f32_16x16x32_f16(aH, bH, accH[nt], 0, 0, 0);
        }
    }

    // Epilogue: direct global writes (64B-coalesced per 16-lane group)
#pragma unroll
    for (int nt = 0; nt < 4; ++nt) {
        int n = nh * 64 + nt * 16 + (l & 15);
        float scb = b1s[n], shb = b1h[n];
        float xv[4];
        if (XSRC == 0) {
            const float* xp = xf + ((size_t)(b * C0 + n)) * HW + p0 + mt * 16 + (l >> 4) * 4;
            f32x4 x4 = *(const f32x4*)xp;
#pragma unroll
            for (int r = 0; r < 4; ++r) xv[r] = x4[r];
        } else {
#pragma unroll
            for (int r = 0; r < 4; ++r)
                xv[r] = xT[((size_t)(b * HW + p0 + mt * 16 + (l >> 4) * 4 + r)) * C0 + n];
        }
#pragma unroll
        for (int r = 0; r < 4; ++r) {
            float scale = accS[nt][r] + scb + 1.f;
            float shift = accH[nt][r] + shb;
            outT[((size_t)(b * HW + p0 + mt * 16 + (l >> 4) * 4 + r)) * C0 + n]
                = xv[r] * scale + shift;
        }
    }
}

// ---------------------------------------------------------------------------
// Deformable conv 3x3, split-f16 3-term MFMA, v4: occupancy-first.
//  - no B LDS: weight fragments loaded global->VGPR per lane (L1/L2-hot)
//  - LDS = A(hi/lo) + coords = 44 KB -> 3 blocks/CU; all 576 blocks co-resident
//  - 2 barriers per tap
// MODE 0: ReLU -> f32 [B,HW,128].  MODE 1: + bias + x0 -> f32 [B,128,HW].
template <int MODE>
__global__ __launch_bounds__(512, 6) void k_deform6(
    const float* __restrict__ srcT,  // [B,HW,128] f32
    const float* __restrict__ off,   // [B,18,HW]
    const u16* __restrict__ whi,     // [9][128 o][128 c] f16 hi
    const u16* __restrict__ wlo,     // [9][128 o][128 c] f16 lo
    const float* __restrict__ bias,
    const float* __restrict__ x0,
    float* __restrict__ outF,        // MODE 1
    float* __restrict__ outT)        // MODE 0
{
    constexpr int S = 136;                             // padded u16 stride
    __shared__ __align__(16) u16   asm_[2 * 64 * S];   // 34,816 B (A hi|lo)
    __shared__ __align__(16) u16   cidx[9 * 64 * 4];   // 4,608 B
    __shared__ __align__(16) float cwt[9 * 64 * 2];    // 4,608 B
    u16* a_hi = asm_;
    u16* a_lo = asm_ + 64 * S;

    int bx = blockIdx.x;
    bx = (bx & 7) * (NTILE / 8) + (bx >> 3);           // XCD swizzle
    int b = bx / TPB, p0 = (bx % TPB) * PT;
    int tid = threadIdx.x, l = tid & 63;
    int w = __builtin_amdgcn_readfirstlane(tid >> 6);
    f32x4 zz = {0.f, 0.f, 0.f, 0.f};

    // Phase 0: coords for all 9 taps
    for (int e = tid; e < 9 * 64; e += 512) {
        int k = e >> 6, pp = e & 63;
        int pos = p0 + pp, h = pos / W_, wc = pos % W_;
        float dy = off[((size_t)(b * 18 + 2 * k)) * HW + pos];
        float dx = off[((size_t)(b * 18 + 2 * k + 1)) * HW + pos];
        float py = dy + (float)(h + k / 3 - 1);
        float px = dx + (float)(wc + k % 3 - 1);
        float yf = floorf(py), xf = floorf(px);
        int y0 = (int)yf, x0i = (int)xf;
        cwt[e * 2]     = py - yf;
        cwt[e * 2 + 1] = px - xf;
        int iy0 = min(max(y0, 0), H_ - 1),     iy1 = min(max(y0 + 1, 0), H_ - 1);
        int ix0 = min(max(x0i, 0), W_ - 1),    ix1 = min(max(x0i + 1, 0), W_ - 1);
        bool vy0 = (y0 >= 0) & (y0 < H_),      vy1 = (y0 + 1 >= 0) & (y0 + 1 < H_);
        bool vx0 = (x0i >= 0) & (x0i < W_),    vx1 = (x0i + 1 >= 0) & (x0i + 1 < W_);
        cidx[e * 4 + 0] = (u16)(iy0 * W_ + ix0) | ((vy0 & vx0) ? 0x8000 : 0);
        cidx[e * 4 + 1] = (u16)(iy0 * W_ + ix1) | ((vy0 & vx1) ? 0x8000 : 0);
        cidx[e * 4 + 2] = (u16)(iy1 * W_ + ix0) | ((vy1 & vx0) ? 0x8000 : 0);
        cidx[e * 4 + 3] = (u16)(iy1 * W_ + ix1) | ((vy1 & vx1) ? 0x8000 : 0);
    }
    __syncthreads();

    f32x4 acc[4];
#pragma unroll
    for (int ot = 0; ot < 4; ++ot) acc[ot] = zz;

    int mt = w & 3, ng = w >> 2;          // 4 m-tiles x 2 n-halves (64 ch)
    int pos_r = mt * 16 + (l & 15);
    const float* lbase = srcT + (size_t)b * HW * C0 + 2 * l;

    for (int k = 0; k < 9; ++k) {
        // Gather+commit: wave w -> positions w*8..w*8+7, 2 channels per lane
#pragma unroll
        for (int i = 0; i < 8; ++i) {
            int pp = w * 8 + i, e = k * 64 + pp;
            u32 c01 = *(const u32*)&cidx[e * 4];
            u32 c23 = *(const u32*)&cidx[e * 4 + 2];
            f32x2 v0 = *(const f32x2*)(lbase + (size_t)(c01 & 0x3fffu) * C0);
            f32x2 v1 = *(const f32x2*)(lbase + (size_t)((c01 >> 16) & 0x3fffu) * C0);
            f32x2 v2 = *(const f32x2*)(lbase + (size_t)(c23 & 0x3fffu) * C0);
            f32x2 v3 = *(const f32x2*)(lbase + (size_t)((c23 >> 16) & 0x3fffu) * C0);
            float wy = cwt[e * 2], wx = cwt[e * 2 + 1];
            float aa  = wy * wx;
            float w11 = (c23 & 0x80000000u) ? aa : 0.f;
            float w10 = (c23 & 0x8000u) ? (wy - aa) : 0.f;
            float w01 = (c01 & 0x80000000u) ? (wx - aa) : 0.f;
            float w00 = (c01 & 0x8000u) ? (1.f - wy - wx + aa) : 0.f;
            float s0 = v0[0] * w00 + v1[0] * w01 + v2[0] * w10 + v3[0] * w11;
            float s1 = v0[1] * w00 + v1[1] * w01 + v2[1] * w10 + v3[1] * w11;
            _Float16 h0 = (_Float16)s0, h1 = (_Float16)s1;
            float r0 = s0 - (float)h0, r1 = s1 - (float)h1;
            u32 hv = (u32)__builtin_bit_cast(u16, h0)
                   | ((u32)__builtin_bit_cast(u16, h1) << 16);
            u32 lv = (u32)f2h(r0) | ((u32)f2h(r1) << 16);
            *(u32*)&a_hi[pp * S + 2 * l] = hv;
            *(u32*)&a_lo[pp * S + 2 * l] = lv;
        }
        __syncthreads();                  // publish A(k)

        // MFMA phase: B fragments straight from global (per-lane 16B loads)
#pragma unroll
        for (int ks = 0; ks < 4; ++ks) {
            int kb = ks * 32 + (l >> 4) * 8;
            int ai = pos_r * S + kb;
            f16x8 ah = *(const f16x8*)&a_hi[ai];
            f16x8 al = *(const f16x8*)&a_lo[ai];
#pragma unroll
            for (int ot = 0; ot < 4; ++ot) {
                int orow = ng * 64 + ot * 16 + (l & 15);
                size_t wi = ((size_t)k * C0 + orow) * C0 + kb;
                f16x8 bh = *(const f16x8*)&whi[wi];
                f16x8 bl = *(const f16x8*)&wlo[wi];
                acc[ot] = __builtin_amdgcn_mfma_f32_16x16x32_f16(ah, bh, acc[ot], 0, 0, 0);
                acc[ot] = __builtin_amdgcn_mfma_f32_16x16x32_f16(al, bh, acc[ot], 0, 0, 0);
                acc[ot] = __builtin_amdgcn_mfma_f32_16x16x32_f16(ah, bl, acc[ot], 0, 0, 0);
            }
        }
        __syncthreads();                  // A reads done before next overwrite
    }

    if (MODE == 0) {
        float* otile = (float*)asm_;      // [64][132] f32 = 33,792 B fits
#pragma unroll
        for (int ot = 0; ot < 4; ++ot) {
            int o = ng * 64 + ot * 16 + (l & 15);
            float bv = bias[o];
#pragma unroll
            for (int r = 0; r < 4; ++r) {
                float v = acc[ot][r] + bv;
                v = v > 0.f ? v : 0.f;
                otile[(mt * 16 + (l >> 4) * 4 + r) * 132 + o] = v;
            }
        }
        __syncthreads();
        float* dst = outT + ((size_t)(b * HW + p0)) * C0;
        for (int i = tid; i < 2048; i += 512) {
            int row = i >> 5, c = i & 31;
            *(f32x4*)&dst[row * 128 + c * 4] = *(const f32x4*)&otile[row * 132 + c * 4];
        }
    } else {
#pragma unroll
        for (int ot = 0; ot < 4; ++ot) {
            int o = ng * 64 + ot * 16 + (l & 15);
            float bv = bias[o];
            size_t base_o = ((size_t)(b * C0 + o)) * HW + p0 + mt * 16 + (l >> 4) * 4;
            f32x4 x4 = *(const f32x4*)(x0 + base_o);
            f32x4 ov;
#pragma unroll
            for (int r = 0; r < 4; ++r) ov[r] = acc[ot][r] + bv + x4[r];
            *(f32x4*)(outF + base_o) = ov;
        }
    }
}

// ---------------------------------------------------------------------------
// Workspace layout (bytes)
constexpr size_t WB_OFF   = 0;            // f32 [B,18,HW]        2,654,208
constexpr size_t WB_WOFFT = 2654208;      // f32 [128][162]          82,944
constexpr size_t WB_W0H   = 2737152;      // f16 [4][128][32]        32,768
constexpr size_t WB_W1H   = 2769920;      // f16 [4][128][128]      131,072
constexpr size_t WB_WDHI  = 2900992;      // f16 [2][9][128][128] 1,179,648
constexpr size_t WB_WDLO  = 4080640;      // f16 [2][9][128][128] 1,179,648
constexpr size_t WB_TA    = 5260288;      // f32 [B,HW,128]      18,874,368
constexpr size_t WB_TB    = 24134656;     // f32 [B,HW,128]      18,874,368
// total 43,009,024 B

extern "C" void kernel_launch(void* const* d_in, const int* in_sizes, int n_in,
                              void* d_out, int out_size, void* d_ws, size_t ws_size,
                              hipStream_t stream)
{
    const float* x0      = (const float*)d_in[0];
    const float* x1      = (const float*)d_in[1];
    const float* w_off   = (const float*)d_in[2];
    const float* b_off   = (const float*)d_in[3];
    const float* s1_sc0w = (const float*)d_in[4];
    const float* s1_sc0b = (const float*)d_in[5];
    const float* s1_sc1w = (const float*)d_in[6];
    const float* s1_sc1b = (const float*)d_in[7];
    const float* s1_sh0w = (const float*)d_in[8];
    const float* s1_sh0b = (const float*)d_in[9];
    const float* s1_sh1w = (const float*)d_in[10];
    const float* s1_sh1b = (const float*)d_in[11];
    const float* w_d1    = (const float*)d_in[12];
    const float* b_d1    = (const float*)d_in[13];
    const float* s2_sc0w = (const float*)d_in[14];
    const float* s2_sc0b = (const float*)d_in[15];
    const float* s2_sc1w = (const float*)d_in[16];
    const float* s2_sc1b = (const float*)d_in[17];
    const float* s2_sh0w = (const float*)d_in[18];
    const float* s2_sh0b = (const float*)d_in[19];
    const float* s2_sh1w = (const float*)d_in[20];
    const float* s2_sh1b = (const float*)d_in[21];
    const float* w_d2    = (const float*)d_in[22];
    const float* b_d2    = (const float*)d_in[23];

    char* wsb = (char*)d_ws;
    float* off   = (float*)(wsb + WB_OFF);
    float* wofft = (float*)(wsb + WB_WOFFT);
    u16*   w0h   = (u16*)(wsb + WB_W0H);
    u16*   w1h   = (u16*)(wsb + WB_W1H);
    u16*   wdhi  = (u16*)(wsb + WB_WDHI);
    u16*   wdlo  = (u16*)(wsb + WB_WDLO);
    float* TA    = (float*)(wsb + WB_TA);
    float* TB    = (float*)(wsb + WB_TB);

    k_prep<<<1152, 256, 0, stream>>>(w_off, w_d1, w_d2,
                                     s1_sc0w, s1_sh0w, s2_sc0w, s2_sh0w,
                                     s1_sc1w, s1_sh1w, s2_sc1w, s2_sh1w,
                                     wofft, wdhi, wdlo, w0h, w1h);
    k_conv_off<<<NTILE, 256, 0, stream>>>(x0, wofft, b_off, off);
    // SFT1: x = x0 (channel-major) -> TA (position-major)
    k_sft_mma<0><<<NTILE, 512, 0, stream>>>(x0, nullptr, x1,
                                            w0h, w0h + 4096,
                                            w1h, w1h + 16384,
                                            s1_sc0b, s1_sh0b, s1_sc1b, s1_sh1b, TA);
    // dconv1: gather TA -> relu -> TB (position-major)
    k_deform6<0><<<NTILE, 512, 0, stream>>>(TA, off, wdhi, wdlo, b_d1,
                                            nullptr, nullptr, TB);
    // SFT2: x = TB (position-major) -> TA (position-major)
    k_sft_mma<1><<<NTILE, 512, 0, stream>>>(nullptr, TB, x1,
                                            w0h + 8192, w0h + 12288,
                                            w1h + 32768, w1h + 49152,
                                            s2_sc0b, s2_sh0b, s2_sc1b, s2_sh1b, TA);
    // dconv2: gather TA -> +bias +x0 -> d_out (channel-major)
    k_deform6<1><<<NTILE, 512, 0, stream>>>(TA, off, wdhi + 9 * 16384, wdlo + 9 * 16384,
                                            b_d2, x0, (float*)d_out, nullptr);
}

// Round 12
// 583.230 us; speedup vs baseline: 1.0918x; 1.0918x over previous
//
#include <hip/hip_runtime.h>

typedef unsigned short u16;
typedef unsigned int   u32;
typedef __attribute__((ext_vector_type(8))) _Float16 f16x8;
typedef __attribute__((ext_vector_type(2))) float f32x2;
typedef __attribute__((ext_vector_type(4))) float f32x4;
typedef __attribute__((ext_vector_type(4))) unsigned int u32x4;

constexpr int B_  = 4;
constexpr int C0  = 128;
constexpr int C1  = 32;
constexpr int H_  = 96;
constexpr int W_  = 96;
constexpr int HW  = H_ * W_;        // 9216
constexpr int PT  = 64;
constexpr int TPB = HW / PT;        // 144
constexpr int NTILE = B_ * TPB;     // 576

__device__ inline u16 f2h(float f) {
    _Float16 h = (_Float16)f;
    return __builtin_bit_cast(u16, h);
}

// ---------------------------------------------------------------------------
// Weight prep (unchanged)
__global__ __launch_bounds__(256) void k_prep(
    const float* __restrict__ w_off,
    const float* __restrict__ wd1,  const float* __restrict__ wd2,
    const float* __restrict__ s1c0, const float* __restrict__ s1h0,
    const float* __restrict__ s2c0, const float* __restrict__ s2h0,
    const float* __restrict__ s1c1, const float* __restrict__ s1h1,
    const float* __restrict__ s2c1, const float* __restrict__ s2h1,
    float* __restrict__ wofft, u16* __restrict__ wdhi, u16* __restrict__ wdlo,
    u16* __restrict__ w0h,     u16* __restrict__ w1h)
{
    int t = blockIdx.x * 256 + threadIdx.x;
    if (t < C0 * 18 * 9) {
        int c = t / 162, r = t % 162, o = r / 9, tap = r % 9;
        wofft[t] = w_off[(o * C0 + c) * 9 + tap];
    }
    if (t < 2 * 9 * C0 * C0) {
        int d = t / (9 * C0 * C0), r = t % (9 * C0 * C0);
        int k = r / (C0 * C0), r2 = r % (C0 * C0), o = r2 / C0, c = r2 % C0;
        const float* wsrc = d ? wd2 : wd1;
        float wv = wsrc[(o * C0 + c) * 9 + k];
        _Float16 hi = (_Float16)wv;
        float rr = wv - (float)hi;
        wdhi[t] = __builtin_bit_cast(u16, hi);
        wdlo[t] = f2h(rr);
    }
    if (t < 4 * C0 * C1) {
        int m = t / (C0 * C1), i = t % (C0 * C1);
        const float* s = (m == 0) ? s1c0 : (m == 1) ? s1h0 : (m == 2) ? s2c0 : s2h0;
        w0h[t] = f2h(s[i]);
    }
    if (t < 4 * C0 * C0) {
        int m = t / (C0 * C0), i = t % (C0 * C0);
        const float* s = (m == 0) ? s1c1 : (m == 1) ? s1h1 : (m == 2) ? s2c1 : s2h1;
        w1h[t] = f2h(s[i]);
    }
}

// ---------------------------------------------------------------------------
// Offset conv: 3x3, 128 -> 18 (f32, round-1 proven)
__global__ __launch_bounds__(256) void k_conv_off(
    const float* __restrict__ x0, const float* __restrict__ wofft,
    const float* __restrict__ boff, float* __restrict__ off)
{
    int bx = blockIdx.x;
    int b  = bx / TPB;
    int p0 = (bx % TPB) * PT;
    int tid = threadIdx.x;
    int p   = tid & 63;
    int cq  = __builtin_amdgcn_readfirstlane(tid >> 6);
    int pos = p0 + p;
    int h = pos / W_, w = pos % W_;

    float acc[18];
#pragma unroll
    for (int o = 0; o < 18; ++o) acc[o] = 0.f;

    for (int cc = 0; cc < 32; ++cc) {
        int c = cq * 32 + cc;
        const float* xb = x0 + ((size_t)(b * C0 + c)) * HW;
        float v[9];
#pragma unroll
        for (int t = 0; t < 9; ++t) {
            int dy = t / 3 - 1, dx = t % 3 - 1;
            int hy = h + dy, wx = w + dx;
            bool ok = (hy >= 0) & (hy < H_) & (wx >= 0) & (wx < W_);
            v[t] = ok ? xb[hy * W_ + wx] : 0.f;
        }
        const float* wr = wofft + c * 162;
#pragma unroll
        for (int o = 0; o < 18; ++o)
#pragma unroll
            for (int t = 0; t < 9; ++t)
                acc[o] = fmaf(wr[o * 9 + t], v[t], acc[o]);
    }

    __shared__ float red[4][18][PT];
#pragma unroll
    for (int o = 0; o < 18; ++o) red[cq][o][p] = acc[o];
    __syncthreads();
    for (int idx = tid; idx < 18 * PT; idx += 256) {
        int o = idx / PT, pp = idx % PT;
        float s = red[0][o][pp] + red[1][o][pp] + red[2][o][pp] + red[3][o][pp]
                + boff[o];
        off[((size_t)(b * 18 + o)) * HW + p0 + pp] = s;
    }
}

// ---------------------------------------------------------------------------
// Fused SFT via MFMA (round-11 version; proven absmax 0.0156)
template <int XSRC>
__global__ __launch_bounds__(512, 6) void k_sft_mma(
    const float* __restrict__ xf,     // XSRC==0
    const float* __restrict__ xT,     // XSRC==1
    const float* __restrict__ x1,
    const u16* __restrict__ w0s, const u16* __restrict__ w0h,   // [128 hid][32 ch]
    const u16* __restrict__ w1s, const u16* __restrict__ w1h,   // [128 out][128 hid]
    const float* __restrict__ b0s, const float* __restrict__ b0h,
    const float* __restrict__ b1s, const float* __restrict__ b1h,
    float* __restrict__ outT)         // [B,HW,128]
{
    __shared__ __align__(16) u16 x1t[64 * 32];
    __shared__ __align__(16) u16 hidt[2][64 * 128];

    int bx = blockIdx.x, b = bx / TPB, p0 = (bx % TPB) * PT;
    int tid = threadIdx.x, l = tid & 63;
    int w = __builtin_amdgcn_readfirstlane(tid >> 6);
    f32x4 zz = {0.f, 0.f, 0.f, 0.f};

    for (int i = tid; i < C1 * PT; i += 512) {
        int ch = i >> 6, pos = i & 63;
        float v = x1[((size_t)(b * C1 + ch)) * HW + p0 + pos];
        x1t[pos * 32 + (ch ^ ((pos & 3) << 3))] = f2h(v);
    }
    __syncthreads();

    {   // hidden GEMM (K=32)
        int mt = w & 3, br = w >> 2;
        int pos = mt * 16 + (l & 15);
        int koff = (l >> 4) * 8;
        f16x8 a = *(const f16x8*)&x1t[pos * 32 + (koff ^ ((pos & 3) << 3))];
        const u16* w0 = br ? w0h : w0s;
        const float* bb = br ? b0h : b0s;
        u16* hrow = hidt[br];
#pragma unroll
        for (int nt = 0; nt < 8; ++nt) {
            int n = nt * 16 + (l & 15);
            f16x8 bfr = *(const f16x8*)&w0[n * 32 + koff];
            f32x4 h = __builtin_amdgcn_mfma_f32_16x16x32_f16(a, bfr, zz, 0, 0, 0);
            float bv = bb[n];
#pragma unroll
            for (int r = 0; r < 4; ++r) {
                float hv = h[r] + bv;
                hv = hv > 0.f ? hv : 0.1f * hv;
                int prow = mt * 16 + (l >> 4) * 4 + r;
                hrow[prow * 128 + (n ^ ((prow & 7) << 3))] = f2h(hv);
            }
        }
    }
    __syncthreads();

    f32x4 accS[4], accH[4];
#pragma unroll
    for (int nt = 0; nt < 4; ++nt) { accS[nt] = zz; accH[nt] = zz; }
    int mt = w & 3, nh = w >> 2;
    int pos = mt * 16 + (l & 15);
#pragma unroll
    for (int ks = 0; ks < 4; ++ks) {
        int kb = ks * 32 + (l >> 4) * 8;
        f16x8 aS = *(const f16x8*)&hidt[0][pos * 128 + (kb ^ ((pos & 7) << 3))];
        f16x8 aH = *(const f16x8*)&hidt[1][pos * 128 + (kb ^ ((pos & 7) << 3))];
#pragma unroll
        for (int nt = 0; nt < 4; ++nt) {
            int n = nh * 64 + nt * 16 + (l & 15);
            f16x8 bS = *(const f16x8*)&w1s[n * 128 + kb];
            f16x8 bH = *(const f16x8*)&w1h[n * 128 + kb];
            accS[nt] = __builtin_amdgcn_mfma_f32_16x16x32_f16(aS, bS, accS[nt], 0, 0, 0);
            accH[nt] = __builtin_amdgcn_mfma_f32_16x16x32_f16(aH, bH, accH[nt], 0, 0, 0);
        }
    }

#pragma unroll
    for (int nt = 0; nt < 4; ++nt) {
        int n = nh * 64 + nt * 16 + (l & 15);
        float scb = b1s[n], shb = b1h[n];
        float xv[4];
        if (XSRC == 0) {
            const float* xp = xf + ((size_t)(b * C0 + n)) * HW + p0 + mt * 16 + (l >> 4) * 4;
            f32x4 x4 = *(const f32x4*)xp;
#pragma unroll
            for (int r = 0; r < 4; ++r) xv[r] = x4[r];
        } else {
#pragma unroll
            for (int r = 0; r < 4; ++r)
                xv[r] = xT[((size_t)(b * HW + p0 + mt * 16 + (l >> 4) * 4 + r)) * C0 + n];
        }
#pragma unroll
        for (int r = 0; r < 4; ++r) {
            float scale = accS[nt][r] + scb + 1.f;
            float shift = accH[nt][r] + shb;
            outT[((size_t)(b * HW + p0 + mt * 16 + (l >> 4) * 4 + r)) * C0 + n]
                = xv[r] * scale + shift;
        }
    }
}

// ---------------------------------------------------------------------------
// Deformable conv 3x3, split-f16 3-term MFMA, v5:
//  - A-fragments gathered straight to registers (lane = its own MFMA fragment)
//  - coords inline in registers (no coord LDS, no commit pass)
//  - B in LDS, halves double-buffered P/Q; lgkm-only raw barriers (2/tap)
// MODE 0: ReLU -> f32 [B,HW,128].  MODE 1: + bias + x0 -> f32 [B,128,HW].
template <int MODE>
__global__ __launch_bounds__(512, 4) void k_deform8(
    const float* __restrict__ srcT,  // [B,HW,128] f32
    const float* __restrict__ off,   // [B,18,HW]
    const u16* __restrict__ whi,     // [9][128 o][128 c] f16 hi
    const u16* __restrict__ wlo,     // [9][128 o][128 c] f16 lo
    const float* __restrict__ bias,
    const float* __restrict__ x0,
    float* __restrict__ outF,        // MODE 1
    float* __restrict__ outT)        // MODE 0
{
    constexpr int S = 136;                              // padded u16 stride
    __shared__ __align__(16) u16 bbuf[2][2][64 * S];    // [P/Q][hi/lo] 69,632 B

    int bx = blockIdx.x;
    bx = (bx & 7) * (NTILE / 8) + (bx >> 3);            // XCD swizzle
    int b = bx / TPB, p0 = (bx % TPB) * PT;
    int tid = threadIdx.x, l = tid & 63;
    int w = __builtin_amdgcn_readfirstlane(tid >> 6);
    int mt = w & 3, ng = w >> 2;
    int kq = l >> 4;                                    // k-quadrant 0..3
    int myp = p0 + mt * 16 + (l & 15);                  // lane's position
    int myh = myp / W_, myw = myp % W_;
    int ch0 = kq * 8;                                   // lane's base channel
    const float* base = srcT + (size_t)b * HW * C0;
    f32x4 zz = {0.f, 0.f, 0.f, 0.f};

    f32x4 acc[2][2];
#pragma unroll
    for (int hf = 0; hf < 2; ++hf)
#pragma unroll
        for (int ot = 0; ot < 2; ++ot) acc[hf][ot] = zz;

    int srow = tid >> 3, sseg = tid & 7;                // B staging mapping
    f16x8 ah[4], al[4];

#define STAGE(KK, HF, BUF)                                                    \
    {                                                                         \
        const u16* sh = whi + ((size_t)(KK) * C0 + (HF) * 64 + srow) * C0 + sseg * 16; \
        const u16* sl = wlo + ((size_t)(KK) * C0 + (HF) * 64 + srow) * C0 + sseg * 16; \
        u16* dh = &bbuf[BUF][0][srow * S + sseg * 16];                        \
        u16* dl = &bbuf[BUF][1][srow * S + sseg * 16];                        \
        *(u32x4*)&dh[0] = *(const u32x4*)&sh[0];                              \
        *(u32x4*)&dh[8] = *(const u32x4*)&sh[8];                              \
        *(u32x4*)&dl[0] = *(const u32x4*)&sl[0];                              \
        *(u32x4*)&dl[8] = *(const u32x4*)&sl[8];                              \
    }

#define GATHER(KK)                                                            \
    {                                                                         \
        float dy = off[((size_t)(b * 18 + 2 * (KK))) * HW + myp];             \
        float dx = off[((size_t)(b * 18 + 2 * (KK) + 1)) * HW + myp];         \
        float py = dy + (float)(myh + (KK) / 3 - 1);                          \
        float px = dx + (float)(myw + (KK) % 3 - 1);                          \
        float yf = floorf(py), xf = floorf(px);                               \
        int y0 = (int)yf, x0i = (int)xf;                                      \
        float wy = py - yf, wx = px - xf;                                     \
        bool vy0 = (y0 >= 0) & (y0 < H_), vy1 = (y0 + 1 >= 0) & (y0 + 1 < H_);\
        bool vx0 = (x0i >= 0) & (x0i < W_), vx1 = (x0i + 1 >= 0) & (x0i + 1 < W_); \
        float aa  = wy * wx;                                                  \
        float w11 = (vy1 & vx1) ? aa : 0.f;                                   \
        float w10 = (vy1 & vx0) ? (wy - aa) : 0.f;                            \
        float w01 = (vy0 & vx1) ? (wx - aa) : 0.f;                            \
        float w00 = (vy0 & vx0) ? (1.f - wy - wx + aa) : 0.f;                 \
        int iy0 = min(max(y0, 0), H_ - 1), iy1 = min(max(y0 + 1, 0), H_ - 1); \
        int ix0 = min(max(x0i, 0), W_ - 1), ix1 = min(max(x0i + 1, 0), W_ - 1); \
        const float* q00 = base + (size_t)(iy0 * W_ + ix0) * C0 + ch0;        \
        const float* q01 = base + (size_t)(iy0 * W_ + ix1) * C0 + ch0;        \
        const float* q10 = base + (size_t)(iy1 * W_ + ix0) * C0 + ch0;        \
        const float* q11 = base + (size_t)(iy1 * W_ + ix1) * C0 + ch0;        \
        _Pragma("unroll")                                                     \
        for (int ks = 0; ks < 4; ++ks) {                                      \
            int cb = ks * 32;                                                 \
            f32x4 a0 = *(const f32x4*)(q00 + cb), a1 = *(const f32x4*)(q00 + cb + 4); \
            f32x4 b0 = *(const f32x4*)(q01 + cb), b1 = *(const f32x4*)(q01 + cb + 4); \
            f32x4 c0 = *(const f32x4*)(q10 + cb), c1 = *(const f32x4*)(q10 + cb + 4); \
            f32x4 d0 = *(const f32x4*)(q11 + cb), d1 = *(const f32x4*)(q11 + cb + 4); \
            f16x8 hh, ll;                                                     \
            _Pragma("unroll")                                                 \
            for (int j = 0; j < 4; ++j) {                                     \
                float s0 = a0[j] * w00 + b0[j] * w01 + c0[j] * w10 + d0[j] * w11; \
                float s1 = a1[j] * w00 + b1[j] * w01 + c1[j] * w10 + d1[j] * w11; \
                _Float16 h0 = (_Float16)s0, h1 = (_Float16)s1;                \
                hh[j] = h0;      hh[j + 4] = h1;                              \
                ll[j] = (_Float16)(s0 - (float)h0);                           \
                ll[j + 4] = (_Float16)(s1 - (float)h1);                       \
            }                                                                 \
            ah[ks] = hh;  al[ks] = ll;                                        \
        }                                                                     \
    }

#define MFMA_H(HF, BUF)                                                       \
    {                                                                         \
        _Pragma("unroll")                                                     \
        for (int ks = 0; ks < 4; ++ks) {                                      \
            int cb = ks * 32 + kq * 8;                                        \
            _Pragma("unroll")                                                 \
            for (int ot = 0; ot < 2; ++ot) {                                  \
                int orl = ng * 32 + ot * 16 + (l & 15);                       \
                f16x8 bh = *(const f16x8*)&bbuf[BUF][0][orl * S + cb];        \
                f16x8 bl = *(const f16x8*)&bbuf[BUF][1][orl * S + cb];        \
                acc[HF][ot] = __builtin_amdgcn_mfma_f32_16x16x32_f16(ah[ks], bh, acc[HF][ot], 0, 0, 0); \
                acc[HF][ot] = __builtin_amdgcn_mfma_f32_16x16x32_f16(al[ks], bh, acc[HF][ot], 0, 0, 0); \
                acc[HF][ot] = __builtin_amdgcn_mfma_f32_16x16x32_f16(ah[ks], bl, acc[HF][ot], 0, 0, 0); \
            }                                                                 \
        }                                                                     \
    }

#define LGKM_BAR                                                              \
    asm volatile("s_waitcnt lgkmcnt(0)" ::: "memory");                        \
    __builtin_amdgcn_s_barrier();

    // Prologue: stage tap0 half0 into P
    STAGE(0, 0, 0)
    LGKM_BAR

    for (int k = 0; k < 9; ++k) {
        GATHER(k)                          // registers only; loads in flight
        STAGE(k, 1, 1)                     // half1 -> Q
        MFMA_H(0, 0)                       // reads P
        LGKM_BAR                           // Q staged; P reads done
        if (k < 8) STAGE(k + 1, 0, 0)      // next tap half0 -> P
        MFMA_H(1, 1)                       // reads Q
        LGKM_BAR                           // P staged; Q reads done
    }
#undef STAGE
#undef GATHER
#undef MFMA_H
#undef LGKM_BAR

    if (MODE == 0) {
        float* otile = (float*)&bbuf[0][0][0];   // [64][132] f32 = 33,792 B
#pragma unroll
        for (int hf = 0; hf < 2; ++hf)
#pragma unroll
            for (int ot = 0; ot < 2; ++ot) {
                int o = hf * 64 + ng * 32 + ot * 16 + (l & 15);
                float bv = bias[o];
#pragma unroll
                for (int r = 0; r < 4; ++r) {
                    float v = acc[hf][ot][r] + bv;
                    v = v > 0.f ? v : 0.f;
                    otile[(mt * 16 + (l >> 4) * 4 + r) * 132 + o] = v;
                }
            }
        __syncthreads();
        float* dst = outT + ((size_t)(b * HW + p0)) * C0;
        for (int i = tid; i < 2048; i += 512) {
            int row = i >> 5, c = i & 31;
            *(f32x4*)&dst[row * 128 + c * 4] = *(const f32x4*)&otile[row * 132 + c * 4];
        }
    } else {
#pragma unroll
        for (int hf = 0; hf < 2; ++hf)
#pragma unroll
            for (int ot = 0; ot < 2; ++ot) {
                int o = hf * 64 + ng * 32 + ot * 16 + (l & 15);
                float bv = bias[o];
                size_t base_o = ((size_t)(b * C0 + o)) * HW + p0 + mt * 16 + (l >> 4) * 4;
                f32x4 x4 = *(const f32x4*)(x0 + base_o);
                f32x4 ov;
#pragma unroll
                for (int r = 0; r < 4; ++r) ov[r] = acc[hf][ot][r] + bv + x4[r];
                *(f32x4*)(outF + base_o) = ov;
            }
    }
}

// ---------------------------------------------------------------------------
// Workspace layout (bytes)
constexpr size_t WB_OFF   = 0;            // f32 [B,18,HW]        2,654,208
constexpr size_t WB_WOFFT = 2654208;      // f32 [128][162]          82,944
constexpr size_t WB_W0H   = 2737152;      // f16 [4][128][32]        32,768
constexpr size_t WB_W1H   = 2769920;      // f16 [4][128][128]      131,072
constexpr size_t WB_WDHI  = 2900992;      // f16 [2][9][128][128] 1,179,648
constexpr size_t WB_WDLO  = 4080640;      // f16 [2][9][128][128] 1,179,648
constexpr size_t WB_TA    = 5260288;      // f32 [B,HW,128]      18,874,368
constexpr size_t WB_TB    = 24134656;     // f32 [B,HW,128]      18,874,368
// total 43,009,024 B

extern "C" void kernel_launch(void* const* d_in, const int* in_sizes, int n_in,
                              void* d_out, int out_size, void* d_ws, size_t ws_size,
                              hipStream_t stream)
{
    const float* x0      = (const float*)d_in[0];
    const float* x1      = (const float*)d_in[1];
    const float* w_off   = (const float*)d_in[2];
    const float* b_off   = (const float*)d_in[3];
    const float* s1_sc0w = (const float*)d_in[4];
    const float* s1_sc0b = (const float*)d_in[5];
    const float* s1_sc1w = (const float*)d_in[6];
    const float* s1_sc1b = (const float*)d_in[7];
    const float* s1_sh0w = (const float*)d_in[8];
    const float* s1_sh0b = (const float*)d_in[9];
    const float* s1_sh1w = (const float*)d_in[10];
    const float* s1_sh1b = (const float*)d_in[11];
    const float* w_d1    = (const float*)d_in[12];
    const float* b_d1    = (const float*)d_in[13];
    const float* s2_sc0w = (const float*)d_in[14];
    const float* s2_sc0b = (const float*)d_in[15];
    const float* s2_sc1w = (const float*)d_in[16];
    const float* s2_sc1b = (const float*)d_in[17];
    const float* s2_sh0w = (const float*)d_in[18];
    const float* s2_sh0b = (const float*)d_in[19];
    const float* s2_sh1w = (const float*)d_in[20];
    const float* s2_sh1b = (const float*)d_in[21];
    const float* w_d2    = (const float*)d_in[22];
    const float* b_d2    = (const float*)d_in[23];

    char* wsb = (char*)d_ws;
    float* off   = (float*)(wsb + WB_OFF);
    float* wofft = (float*)(wsb + WB_WOFFT);
    u16*   w0h   = (u16*)(wsb + WB_W0H);
    u16*   w1h   = (u16*)(wsb + WB_W1H);
    u16*   wdhi  = (u16*)(wsb + WB_WDHI);
    u16*   wdlo  = (u16*)(wsb + WB_WDLO);
    float* TA    = (float*)(wsb + WB_TA);
    float* TB    = (float*)(wsb + WB_TB);

    k_prep<<<1152, 256, 0, stream>>>(w_off, w_d1, w_d2,
                                     s1_sc0w, s1_sh0w, s2_sc0w, s2_sh0w,
                                     s1_sc1w, s1_sh1w, s2_sc1w, s2_sh1w,
                                     wofft, wdhi, wdlo, w0h, w1h);
    k_conv_off<<<NTILE, 256, 0, stream>>>(x0, wofft, b_off, off);
    // SFT1: x = x0 (channel-major) -> TA (position-major)
    k_sft_mma<0><<<NTILE, 512, 0, stream>>>(x0, nullptr, x1,
                                            w0h, w0h + 4096,
                                            w1h, w1h + 16384,
                                            s1_sc0b, s1_sh0b, s1_sc1b, s1_sh1b, TA);
    // dconv1: gather TA -> relu -> TB (position-major)
    k_deform8<0><<<NTILE, 512, 0, stream>>>(TA, off, wdhi, wdlo, b_d1,
                                            nullptr, nullptr, TB);
    // SFT2: x = TB (position-major) -> TA (position-major)
    k_sft_mma<1><<<NTILE, 512, 0, stream>>>(nullptr, TB, x1,
                                            w0h + 8192, w0h + 12288,
                                            w1h + 32768, w1h + 49152,
                                            s2_sc0b, s2_sh0b, s2_sc1b, s2_sh1b, TA);
    // dconv2: gather TA -> +bias +x0 -> d_out (channel-major)
    k_deform8<1><<<NTILE, 512, 0, stream>>>(TA, off, wdhi + 9 * 16384, wdlo + 9 * 16384,
                                            b_d2, x0, (float*)d_out, nullptr);
}

// Round 13
// 418.407 us; speedup vs baseline: 1.5218x; 1.3939x over previous
//
#include <hip/hip_runtime.h>

typedef unsigned short u16;
typedef unsigned int   u32;
typedef __attribute__((ext_vector_type(8))) _Float16 f16x8;
typedef __attribute__((ext_vector_type(2))) float f32x2;
typedef __attribute__((ext_vector_type(4))) float f32x4;
typedef __attribute__((ext_vector_type(4))) unsigned int u32x4;

constexpr int B_  = 4;
constexpr int C0  = 128;
constexpr int C1  = 32;
constexpr int H_  = 96;
constexpr int W_  = 96;
constexpr int HW  = H_ * W_;        // 9216
constexpr int PT  = 64;
constexpr int TPB = HW / PT;        // 144
constexpr int NTILE = B_ * TPB;     // 576

__device__ inline u16 f2h(float f) {
    _Float16 h = (_Float16)f;
    return __builtin_bit_cast(u16, h);
}

// ---------------------------------------------------------------------------
// Weight prep (unchanged)
__global__ __launch_bounds__(256) void k_prep(
    const float* __restrict__ w_off,
    const float* __restrict__ wd1,  const float* __restrict__ wd2,
    const float* __restrict__ s1c0, const float* __restrict__ s1h0,
    const float* __restrict__ s2c0, const float* __restrict__ s2h0,
    const float* __restrict__ s1c1, const float* __restrict__ s1h1,
    const float* __restrict__ s2c1, const float* __restrict__ s2h1,
    float* __restrict__ wofft, u16* __restrict__ wdhi, u16* __restrict__ wdlo,
    u16* __restrict__ w0h,     u16* __restrict__ w1h)
{
    int t = blockIdx.x * 256 + threadIdx.x;
    if (t < C0 * 18 * 9) {
        int c = t / 162, r = t % 162, o = r / 9, tap = r % 9;
        wofft[t] = w_off[(o * C0 + c) * 9 + tap];
    }
    if (t < 2 * 9 * C0 * C0) {
        int d = t / (9 * C0 * C0), r = t % (9 * C0 * C0);
        int k = r / (C0 * C0), r2 = r % (C0 * C0), o = r2 / C0, c = r2 % C0;
        const float* wsrc = d ? wd2 : wd1;
        float wv = wsrc[(o * C0 + c) * 9 + k];
        _Float16 hi = (_Float16)wv;
        float rr = wv - (float)hi;
        wdhi[t] = __builtin_bit_cast(u16, hi);
        wdlo[t] = f2h(rr);
    }
    if (t < 4 * C0 * C1) {
        int m = t / (C0 * C1), i = t % (C0 * C1);
        const float* s = (m == 0) ? s1c0 : (m == 1) ? s1h0 : (m == 2) ? s2c0 : s2h0;
        w0h[t] = f2h(s[i]);
    }
    if (t < 4 * C0 * C0) {
        int m = t / (C0 * C0), i = t % (C0 * C0);
        const float* s = (m == 0) ? s1c1 : (m == 1) ? s1h1 : (m == 2) ? s2c1 : s2h1;
        w1h[t] = f2h(s[i]);
    }
}

// ---------------------------------------------------------------------------
// Offset conv: 3x3, 128 -> 18 (f32, round-1 proven)
__global__ __launch_bounds__(256) void k_conv_off(
    const float* __restrict__ x0, const float* __restrict__ wofft,
    const float* __restrict__ boff, float* __restrict__ off)
{
    int bx = blockIdx.x;
    int b  = bx / TPB;
    int p0 = (bx % TPB) * PT;
    int tid = threadIdx.x;
    int p   = tid & 63;
    int cq  = __builtin_amdgcn_readfirstlane(tid >> 6);
    int pos = p0 + p;
    int h = pos / W_, w = pos % W_;

    float acc[18];
#pragma unroll
    for (int o = 0; o < 18; ++o) acc[o] = 0.f;

    for (int cc = 0; cc < 32; ++cc) {
        int c = cq * 32 + cc;
        const float* xb = x0 + ((size_t)(b * C0 + c)) * HW;
        float v[9];
#pragma unroll
        for (int t = 0; t < 9; ++t) {
            int dy = t / 3 - 1, dx = t % 3 - 1;
            int hy = h + dy, wx = w + dx;
            bool ok = (hy >= 0) & (hy < H_) & (wx >= 0) & (wx < W_);
            v[t] = ok ? xb[hy * W_ + wx] : 0.f;
        }
        const float* wr = wofft + c * 162;
#pragma unroll
        for (int o = 0; o < 18; ++o)
#pragma unroll
            for (int t = 0; t < 9; ++t)
                acc[o] = fmaf(wr[o * 9 + t], v[t], acc[o]);
    }

    __shared__ float red[4][18][PT];
#pragma unroll
    for (int o = 0; o < 18; ++o) red[cq][o][p] = acc[o];
    __syncthreads();
    for (int idx = tid; idx < 18 * PT; idx += 256) {
        int o = idx / PT, pp = idx % PT;
        float s = red[0][o][pp] + red[1][o][pp] + red[2][o][pp] + red[3][o][pp]
                + boff[o];
        off[((size_t)(b * 18 + o)) * HW + p0 + pp] = s;
    }
}

// ---------------------------------------------------------------------------
// Fused SFT via MFMA (round-11 version; proven absmax 0.0156)
template <int XSRC>
__global__ __launch_bounds__(512, 6) void k_sft_mma(
    const float* __restrict__ xf,     // XSRC==0
    const float* __restrict__ xT,     // XSRC==1
    const float* __restrict__ x1,
    const u16* __restrict__ w0s, const u16* __restrict__ w0h,   // [128 hid][32 ch]
    const u16* __restrict__ w1s, const u16* __restrict__ w1h,   // [128 out][128 hid]
    const float* __restrict__ b0s, const float* __restrict__ b0h,
    const float* __restrict__ b1s, const float* __restrict__ b1h,
    float* __restrict__ outT)         // [B,HW,128]
{
    __shared__ __align__(16) u16 x1t[64 * 32];
    __shared__ __align__(16) u16 hidt[2][64 * 128];

    int bx = blockIdx.x, b = bx / TPB, p0 = (bx % TPB) * PT;
    int tid = threadIdx.x, l = tid & 63;
    int w = __builtin_amdgcn_readfirstlane(tid >> 6);
    f32x4 zz = {0.f, 0.f, 0.f, 0.f};

    for (int i = tid; i < C1 * PT; i += 512) {
        int ch = i >> 6, pos = i & 63;
        float v = x1[((size_t)(b * C1 + ch)) * HW + p0 + pos];
        x1t[pos * 32 + (ch ^ ((pos & 3) << 3))] = f2h(v);
    }
    __syncthreads();

    {   // hidden GEMM (K=32)
        int mt = w & 3, br = w >> 2;
        int pos = mt * 16 + (l & 15);
        int koff = (l >> 4) * 8;
        f16x8 a = *(const f16x8*)&x1t[pos * 32 + (koff ^ ((pos & 3) << 3))];
        const u16* w0 = br ? w0h : w0s;
        const float* bb = br ? b0h : b0s;
        u16* hrow = hidt[br];
#pragma unroll
        for (int nt = 0; nt < 8; ++nt) {
            int n = nt * 16 + (l & 15);
            f16x8 bfr = *(const f16x8*)&w0[n * 32 + koff];
            f32x4 h = __builtin_amdgcn_mfma_f32_16x16x32_f16(a, bfr, zz, 0, 0, 0);
            float bv = bb[n];
#pragma unroll
            for (int r = 0; r < 4; ++r) {
                float hv = h[r] + bv;
                hv = hv > 0.f ? hv : 0.1f * hv;
                int prow = mt * 16 + (l >> 4) * 4 + r;
                hrow[prow * 128 + (n ^ ((prow & 7) << 3))] = f2h(hv);
            }
        }
    }
    __syncthreads();

    f32x4 accS[4], accH[4];
#pragma unroll
    for (int nt = 0; nt < 4; ++nt) { accS[nt] = zz; accH[nt] = zz; }
    int mt = w & 3, nh = w >> 2;
    int pos = mt * 16 + (l & 15);
#pragma unroll
    for (int ks = 0; ks < 4; ++ks) {
        int kb = ks * 32 + (l >> 4) * 8;
        f16x8 aS = *(const f16x8*)&hidt[0][pos * 128 + (kb ^ ((pos & 7) << 3))];
        f16x8 aH = *(const f16x8*)&hidt[1][pos * 128 + (kb ^ ((pos & 7) << 3))];
#pragma unroll
        for (int nt = 0; nt < 4; ++nt) {
            int n = nh * 64 + nt * 16 + (l & 15);
            f16x8 bS = *(const f16x8*)&w1s[n * 128 + kb];
            f16x8 bH = *(const f16x8*)&w1h[n * 128 + kb];
            accS[nt] = __builtin_amdgcn_mfma_f32_16x16x32_f16(aS, bS, accS[nt], 0, 0, 0);
            accH[nt] = __builtin_amdgcn_mfma_f32_16x16x32_f16(aH, bH, accH[nt], 0, 0, 0);
        }
    }

#pragma unroll
    for (int nt = 0; nt < 4; ++nt) {
        int n = nh * 64 + nt * 16 + (l & 15);
        float scb = b1s[n], shb = b1h[n];
        float xv[4];
        if (XSRC == 0) {
            const float* xp = xf + ((size_t)(b * C0 + n)) * HW + p0 + mt * 16 + (l >> 4) * 4;
            f32x4 x4 = *(const f32x4*)xp;
#pragma unroll
            for (int r = 0; r < 4; ++r) xv[r] = x4[r];
        } else {
#pragma unroll
            for (int r = 0; r < 4; ++r)
                xv[r] = xT[((size_t)(b * HW + p0 + mt * 16 + (l >> 4) * 4 + r)) * C0 + n];
        }
#pragma unroll
        for (int r = 0; r < 4; ++r) {
            float scale = accS[nt][r] + scb + 1.f;
            float shift = accH[nt][r] + shb;
            outT[((size_t)(b * HW + p0 + mt * 16 + (l >> 4) * 4 + r)) * C0 + n]
                = xv[r] * scale + shift;
        }
    }
}

// ---------------------------------------------------------------------------
// Deformable conv 3x3, split-f16 3-term MFMA, v6: single-block deep pipeline.
//  - A double-buffered in LDS; B whole-tap in LDS; 2 lgkm-only barriers/tap
//  - gathers + weight loads issued one FULL tap ahead into registers,
//    pinned with sched_barrier; committed to LDS mid-tap (T14)
//  - wave tile M=32 x N=32 -> 12 MFMA per 8 ds_reads; setprio on MFMA (T5)
// MODE 0: ReLU -> f32 [B,HW,128].  MODE 1: + bias + x0 -> f32 [B,128,HW].
template <int MODE>
__global__ __launch_bounds__(512) void k_deform9(
    const float* __restrict__ srcT,  // [B,HW,128] f32
    const float* __restrict__ off,   // [B,18,HW]
    const u16* __restrict__ whi,     // [9][128 o][128 c] f16 hi
    const u16* __restrict__ wlo,     // [9][128 o][128 c] f16 lo
    const float* __restrict__ bias,
    const float* __restrict__ x0,
    float* __restrict__ outF,        // MODE 1
    float* __restrict__ outT)        // MODE 0
{
    constexpr int S = 136;                               // padded u16 stride
    __shared__ __align__(16) u16   a_buf[2][2][64 * S];  // 69,632 B (dbuf x hi/lo)
    __shared__ __align__(16) u16   b_buf[2][128 * S];    // 69,632 B (hi/lo, whole tap)
    __shared__ __align__(16) u16   cidx[9 * 64 * 4];     // 4,608 B
    __shared__ __align__(16) float cwt[9 * 64 * 2];      // 4,608 B  -> total 148,480 B

    int bx = blockIdx.x;
    bx = (bx & 7) * (NTILE / 8) + (bx >> 3);             // XCD swizzle
    int b = bx / TPB, p0 = (bx % TPB) * PT;
    int tid = threadIdx.x, l = tid & 63;
    int w = __builtin_amdgcn_readfirstlane(tid >> 6);
    f32x4 zz = {0.f, 0.f, 0.f, 0.f};

    // Phase 0: coords for all 9 taps (computed once)
    for (int e = tid; e < 9 * 64; e += 512) {
        int k = e >> 6, pp = e & 63;
        int pos = p0 + pp, h = pos / W_, wc = pos % W_;
        float dy = off[((size_t)(b * 18 + 2 * k)) * HW + pos];
        float dx = off[((size_t)(b * 18 + 2 * k + 1)) * HW + pos];
        float py = dy + (float)(h + k / 3 - 1);
        float px = dx + (float)(wc + k % 3 - 1);
        float yf = floorf(py), xf = floorf(px);
        int y0 = (int)yf, x0i = (int)xf;
        cwt[e * 2]     = py - yf;
        cwt[e * 2 + 1] = px - xf;
        int iy0 = min(max(y0, 0), H_ - 1),     iy1 = min(max(y0 + 1, 0), H_ - 1);
        int ix0 = min(max(x0i, 0), W_ - 1),    ix1 = min(max(x0i + 1, 0), W_ - 1);
        bool vy0 = (y0 >= 0) & (y0 < H_),      vy1 = (y0 + 1 >= 0) & (y0 + 1 < H_);
        bool vx0 = (x0i >= 0) & (x0i < W_),    vx1 = (x0i + 1 >= 0) & (x0i + 1 < W_);
        cidx[e * 4 + 0] = (u16)(iy0 * W_ + ix0) | ((vy0 & vx0) ? 0x8000 : 0);
        cidx[e * 4 + 1] = (u16)(iy0 * W_ + ix1) | ((vy0 & vx1) ? 0x8000 : 0);
        cidx[e * 4 + 2] = (u16)(iy1 * W_ + ix0) | ((vy1 & vx0) ? 0x8000 : 0);
        cidx[e * 4 + 3] = (u16)(iy1 * W_ + ix1) | ((vy1 & vx1) ? 0x8000 : 0);
    }
    __syncthreads();

    f32x4 acc[2][2];
#pragma unroll
    for (int ms = 0; ms < 2; ++ms)
#pragma unroll
        for (int ns = 0; ns < 2; ++ns) acc[ms][ns] = zz;

    int mh = w & 1, ng = w >> 1;          // wave: M-half (32 pos), N-quarter (32 out)
    int kq = l >> 4;
    const float* lbase = srcT + (size_t)b * HW * C0 + 2 * l;
    int wrow = tid >> 2, wseg = tid & 3;  // B staging: row, 64B segment

    f32x2 gv[8][4];                       // in-flight A corners (64 VGPR)
    u32x4 wbh[4], wbl[4];                 // in-flight B weights (32 VGPR)

#define ISSUE_G(KK)                                                           \
    {                                                                         \
        int ek = (KK) * 64 + w * 8;                                           \
        _Pragma("unroll")                                                     \
        for (int i = 0; i < 8; ++i) {                                         \
            int e = ek + i;                                                   \
            u32 c01 = *(const u32*)&cidx[e * 4];                              \
            u32 c23 = *(const u32*)&cidx[e * 4 + 2];                          \
            gv[i][0] = *(const f32x2*)(lbase + (size_t)(c01 & 0x3fffu) * C0); \
            gv[i][1] = *(const f32x2*)(lbase + (size_t)((c01 >> 16) & 0x3fffu) * C0); \
            gv[i][2] = *(const f32x2*)(lbase + (size_t)(c23 & 0x3fffu) * C0); \
            gv[i][3] = *(const f32x2*)(lbase + (size_t)((c23 >> 16) & 0x3fffu) * C0); \
        }                                                                     \
        __builtin_amdgcn_sched_barrier(0);                                    \
    }

#define ISSUE_W(KK)                                                           \
    {                                                                         \
        const u16* sh = whi + (size_t)(KK) * 16384 + wrow * 128 + wseg * 32;  \
        const u16* sl = wlo + (size_t)(KK) * 16384 + wrow * 128 + wseg * 32;  \
        _Pragma("unroll")                                                     \
        for (int j = 0; j < 4; ++j) {                                         \
            wbh[j] = *(const u32x4*)&sh[j * 8];                               \
            wbl[j] = *(const u32x4*)&sl[j * 8];                               \
        }                                                                     \
        __builtin_amdgcn_sched_barrier(0);                                    \
    }

#define COMMIT_A(KK, D)                                                       \
    {                                                                         \
        int ek = (KK) * 64 + w * 8;                                           \
        _Pragma("unroll")                                                     \
        for (int i = 0; i < 8; ++i) {                                         \
            int e = ek + i, pp = w * 8 + i;                                   \
            u32 c01 = *(const u32*)&cidx[e * 4];                              \
            u32 c23 = *(const u32*)&cidx[e * 4 + 2];                          \
            float wy = cwt[e * 2], wx = cwt[e * 2 + 1];                       \
            float aa  = wy * wx;                                              \
            float w11 = (c23 & 0x80000000u) ? aa : 0.f;                       \
            float w10 = (c23 & 0x8000u) ? (wy - aa) : 0.f;                    \
            float w01 = (c01 & 0x80000000u) ? (wx - aa) : 0.f;                \
            float w00 = (c01 & 0x8000u) ? (1.f - wy - wx + aa) : 0.f;         \
            float s0 = gv[i][0][0] * w00 + gv[i][1][0] * w01                  \
                     + gv[i][2][0] * w10 + gv[i][3][0] * w11;                 \
            float s1 = gv[i][0][1] * w00 + gv[i][1][1] * w01                  \
                     + gv[i][2][1] * w10 + gv[i][3][1] * w11;                 \
            _Float16 h0 = (_Float16)s0, h1 = (_Float16)s1;                    \
            float r0 = s0 - (float)h0, r1 = s1 - (float)h1;                   \
            u32 hv = (u32)__builtin_bit_cast(u16, h0)                         \
                   | ((u32)__builtin_bit_cast(u16, h1) << 16);                \
            u32 lv = (u32)f2h(r0) | ((u32)f2h(r1) << 16);                     \
            *(u32*)&a_buf[D][0][pp * S + 2 * l] = hv;                         \
            *(u32*)&a_buf[D][1][pp * S + 2 * l] = lv;                         \
        }                                                                     \
    }

#define WRITE_B()                                                             \
    {                                                                         \
        _Pragma("unroll")                                                     \
        for (int j = 0; j < 4; ++j) {                                         \
            *(u32x4*)&b_buf[0][wrow * S + wseg * 32 + j * 8] = wbh[j];        \
            *(u32x4*)&b_buf[1][wrow * S + wseg * 32 + j * 8] = wbl[j];        \
        }                                                                     \
    }

#define MFMA_KS(KS, D)                                                        \
    {                                                                         \
        int kb = (KS) * 32 + kq * 8;                                          \
        f16x8 ah0 = *(const f16x8*)&a_buf[D][0][(mh * 32 + (l & 15)) * S + kb];      \
        f16x8 al0 = *(const f16x8*)&a_buf[D][1][(mh * 32 + (l & 15)) * S + kb];      \
        f16x8 ah1 = *(const f16x8*)&a_buf[D][0][(mh * 32 + 16 + (l & 15)) * S + kb]; \
        f16x8 al1 = *(const f16x8*)&a_buf[D][1][(mh * 32 + 16 + (l & 15)) * S + kb]; \
        f16x8 bh0 = *(const f16x8*)&b_buf[0][(ng * 32 + (l & 15)) * S + kb];         \
        f16x8 bl0 = *(const f16x8*)&b_buf[1][(ng * 32 + (l & 15)) * S + kb];         \
        f16x8 bh1 = *(const f16x8*)&b_buf[0][(ng * 32 + 16 + (l & 15)) * S + kb];    \
        f16x8 bl1 = *(const f16x8*)&b_buf[1][(ng * 32 + 16 + (l & 15)) * S + kb];    \
        acc[0][0] = __builtin_amdgcn_mfma_f32_16x16x32_f16(ah0, bh0, acc[0][0], 0, 0, 0); \
        acc[0][1] = __builtin_amdgcn_mfma_f32_16x16x32_f16(ah0, bh1, acc[0][1], 0, 0, 0); \
        acc[1][0] = __builtin_amdgcn_mfma_f32_16x16x32_f16(ah1, bh0, acc[1][0], 0, 0, 0); \
        acc[1][1] = __builtin_amdgcn_mfma_f32_16x16x32_f16(ah1, bh1, acc[1][1], 0, 0, 0); \
        acc[0][0] = __builtin_amdgcn_mfma_f32_16x16x32_f16(al0, bh0, acc[0][0], 0, 0, 0); \
        acc[0][1] = __builtin_amdgcn_mfma_f32_16x16x32_f16(al0, bh1, acc[0][1], 0, 0, 0); \
        acc[1][0] = __builtin_amdgcn_mfma_f32_16x16x32_f16(al1, bh0, acc[1][0], 0, 0, 0); \
        acc[1][1] = __builtin_amdgcn_mfma_f32_16x16x32_f16(al1, bh1, acc[1][1], 0, 0, 0); \
        acc[0][0] = __builtin_amdgcn_mfma_f32_16x16x32_f16(ah0, bl0, acc[0][0], 0, 0, 0); \
        acc[0][1] = __builtin_amdgcn_mfma_f32_16x16x32_f16(ah0, bl1, acc[0][1], 0, 0, 0); \
        acc[1][0] = __builtin_amdgcn_mfma_f32_16x16x32_f16(ah1, bl0, acc[1][0], 0, 0, 0); \
        acc[1][1] = __builtin_amdgcn_mfma_f32_16x16x32_f16(ah1, bl1, acc[1][1], 0, 0, 0); \
    }

#define LGKM_BAR                                                              \
    asm volatile("s_waitcnt lgkmcnt(0)" ::: "memory");                        \
    __builtin_amdgcn_s_barrier();

    // Prologue: fill pipeline (latency exposed once)
    ISSUE_G(0)
    ISSUE_W(0)
    COMMIT_A(0, 0)
    WRITE_B()
    ISSUE_G(1)
    ISSUE_W(1)
    LGKM_BAR

    for (int k = 0; k < 9; ++k) {
        int d = k & 1;
        __builtin_amdgcn_s_setprio(1);
        MFMA_KS(0, d)
        MFMA_KS(1, d)
        __builtin_amdgcn_s_setprio(0);
        if (k < 8) COMMIT_A(k + 1, d ^ 1)        // consumes gv(k+1)
        __builtin_amdgcn_s_setprio(1);
        MFMA_KS(2, d)
        MFMA_KS(3, d)
        __builtin_amdgcn_s_setprio(0);
        LGKM_BAR                                 // A(k+1) published; B/A(k) reads done
        if (k < 8) WRITE_B()                     // consumes wB(k+1), overwrites B
        if (k < 7) {
            ISSUE_G(k + 2)
            ISSUE_W(k + 2)
        }
        LGKM_BAR                                 // B(k+1) published
    }
#undef ISSUE_G
#undef ISSUE_W
#undef COMMIT_A
#undef WRITE_B
#undef MFMA_KS
#undef LGKM_BAR

    if (MODE == 0) {
        float* otile = (float*)&a_buf[0][0][0];  // [64][132] f32 = 33,792 B
#pragma unroll
        for (int ms = 0; ms < 2; ++ms)
#pragma unroll
            for (int ns = 0; ns < 2; ++ns) {
                int o = ng * 32 + ns * 16 + (l & 15);
                float bv = bias[o];
#pragma unroll
                for (int r = 0; r < 4; ++r) {
                    float v = acc[ms][ns][r] + bv;
                    v = v > 0.f ? v : 0.f;
                    otile[(mh * 32 + ms * 16 + (l >> 4) * 4 + r) * 132 + o] = v;
                }
            }
        __syncthreads();
        float* dst = outT + ((size_t)(b * HW + p0)) * C0;
        for (int i = tid; i < 2048; i += 512) {
            int row = i >> 5, c = i & 31;
            *(f32x4*)&dst[row * 128 + c * 4] = *(const f32x4*)&otile[row * 132 + c * 4];
        }
    } else {
#pragma unroll
        for (int ms = 0; ms < 2; ++ms)
#pragma unroll
            for (int ns = 0; ns < 2; ++ns) {
                int o = ng * 32 + ns * 16 + (l & 15);
                float bv = bias[o];
                size_t base_o = ((size_t)(b * C0 + o)) * HW + p0
                              + mh * 32 + ms * 16 + (l >> 4) * 4;
                f32x4 x4 = *(const f32x4*)(x0 + base_o);
                f32x4 ov;
#pragma unroll
                for (int r = 0; r < 4; ++r) ov[r] = acc[ms][ns][r] + bv + x4[r];
                *(f32x4*)(outF + base_o) = ov;
            }
    }
}

// ---------------------------------------------------------------------------
// Workspace layout (bytes)
constexpr size_t WB_OFF   = 0;            // f32 [B,18,HW]        2,654,208
constexpr size_t WB_WOFFT = 2654208;      // f32 [128][162]          82,944
constexpr size_t WB_W0H   = 2737152;      // f16 [4][128][32]        32,768
constexpr size_t WB_W1H   = 2769920;      // f16 [4][128][128]      131,072
constexpr size_t WB_WDHI  = 2900992;      // f16 [2][9][128][128] 1,179,648
constexpr size_t WB_WDLO  = 4080640;      // f16 [2][9][128][128] 1,179,648
constexpr size_t WB_TA    = 5260288;      // f32 [B,HW,128]      18,874,368
constexpr size_t WB_TB    = 24134656;     // f32 [B,HW,128]      18,874,368
// total 43,009,024 B

extern "C" void kernel_launch(void* const* d_in, const int* in_sizes, int n_in,
                              void* d_out, int out_size, void* d_ws, size_t ws_size,
                              hipStream_t stream)
{
    const float* x0      = (const float*)d_in[0];
    const float* x1      = (const float*)d_in[1];
    const float* w_off   = (const float*)d_in[2];
    const float* b_off   = (const float*)d_in[3];
    const float* s1_sc0w = (const float*)d_in[4];
    const float* s1_sc0b = (const float*)d_in[5];
    const float* s1_sc1w = (const float*)d_in[6];
    const float* s1_sc1b = (const float*)d_in[7];
    const float* s1_sh0w = (const float*)d_in[8];
    const float* s1_sh0b = (const float*)d_in[9];
    const float* s1_sh1w = (const float*)d_in[10];
    const float* s1_sh1b = (const float*)d_in[11];
    const float* w_d1    = (const float*)d_in[12];
    const float* b_d1    = (const float*)d_in[13];
    const float* s2_sc0w = (const float*)d_in[14];
    const float* s2_sc0b = (const float*)d_in[15];
    const float* s2_sc1w = (const float*)d_in[16];
    const float* s2_sc1b = (const float*)d_in[17];
    const float* s2_sh0w = (const float*)d_in[18];
    const float* s2_sh0b = (const float*)d_in[19];
    const float* s2_sh1w = (const float*)d_in[20];
    const float* s2_sh1b = (const float*)d_in[21];
    const float* w_d2    = (const float*)d_in[22];
    const float* b_d2    = (const float*)d_in[23];

    char* wsb = (char*)d_ws;
    float* off   = (float*)(wsb + WB_OFF);
    float* wofft = (float*)(wsb + WB_WOFFT);
    u16*   w0h   = (u16*)(wsb + WB_W0H);
    u16*   w1h   = (u16*)(wsb + WB_W1H);
    u16*   wdhi  = (u16*)(wsb + WB_WDHI);
    u16*   wdlo  = (u16*)(wsb + WB_WDLO);
    float* TA    = (float*)(wsb + WB_TA);
    float* TB    = (float*)(wsb + WB_TB);

    k_prep<<<1152, 256, 0, stream>>>(w_off, w_d1, w_d2,
                                     s1_sc0w, s1_sh0w, s2_sc0w, s2_sh0w,
                                     s1_sc1w, s1_sh1w, s2_sc1w, s2_sh1w,
                                     wofft, wdhi, wdlo, w0h, w1h);
    k_conv_off<<<NTILE, 256, 0, stream>>>(x0, wofft, b_off, off);
    // SFT1: x = x0 (channel-major) -> TA (position-major)
    k_sft_mma<0><<<NTILE, 512, 0, stream>>>(x0, nullptr, x1,
                                            w0h, w0h + 4096,
                                            w1h, w1h + 16384,
                                            s1_sc0b, s1_sh0b, s1_sc1b, s1_sh1b, TA);
    // dconv1: gather TA -> relu -> TB (position-major)
    k_deform9<0><<<NTILE, 512, 0, stream>>>(TA, off, wdhi, wdlo, b_d1,
                                            nullptr, nullptr, TB);
    // SFT2: x = TB (position-major) -> TA (position-major)
    k_sft_mma<1><<<NTILE, 512, 0, stream>>>(nullptr, TB, x1,
                                            w0h + 8192, w0h + 12288,
                                            w1h + 32768, w1h + 49152,
                                            s2_sc0b, s2_sh0b, s2_sc1b, s2_sh1b, TA);
    // dconv2: gather TA -> +bias +x0 -> d_out (channel-major)
    k_deform9<1><<<NTILE, 512, 0, stream>>>(TA, off, wdhi + 9 * 16384, wdlo + 9 * 16384,
                                            b_d2, x0, (float*)d_out, nullptr);
}

// Round 14
// 376.751 us; speedup vs baseline: 1.6901x; 1.1106x over previous
//
#include <hip/hip_runtime.h>

typedef unsigned short u16;
typedef unsigned int   u32;
typedef __attribute__((ext_vector_type(8))) _Float16 f16x8;
typedef __attribute__((ext_vector_type(2))) float f32x2;
typedef __attribute__((ext_vector_type(4))) float f32x4;
typedef __attribute__((ext_vector_type(16))) float f32x16;
typedef __attribute__((ext_vector_type(4))) unsigned int u32x4;

constexpr int B_  = 4;
constexpr int C0  = 128;
constexpr int C1  = 32;
constexpr int H_  = 96;
constexpr int W_  = 96;
constexpr int HW  = H_ * W_;        // 9216
constexpr int PT  = 64;
constexpr int TPB = HW / PT;        // 144
constexpr int NTILE = B_ * TPB;     // 576

__device__ inline u16 f2h(float f) {
    _Float16 h = (_Float16)f;
    return __builtin_bit_cast(u16, h);
}

// ---------------------------------------------------------------------------
// Weight prep (unchanged)
__global__ __launch_bounds__(256) void k_prep(
    const float* __restrict__ w_off,
    const float* __restrict__ wd1,  const float* __restrict__ wd2,
    const float* __restrict__ s1c0, const float* __restrict__ s1h0,
    const float* __restrict__ s2c0, const float* __restrict__ s2h0,
    const float* __restrict__ s1c1, const float* __restrict__ s1h1,
    const float* __restrict__ s2c1, const float* __restrict__ s2h1,
    float* __restrict__ wofft, u16* __restrict__ wdhi, u16* __restrict__ wdlo,
    u16* __restrict__ w0h,     u16* __restrict__ w1h)
{
    int t = blockIdx.x * 256 + threadIdx.x;
    if (t < C0 * 18 * 9) {
        int c = t / 162, r = t % 162, o = r / 9, tap = r % 9;
        wofft[t] = w_off[(o * C0 + c) * 9 + tap];
    }
    if (t < 2 * 9 * C0 * C0) {
        int d = t / (9 * C0 * C0), r = t % (9 * C0 * C0);
        int k = r / (C0 * C0), r2 = r % (C0 * C0), o = r2 / C0, c = r2 % C0;
        const float* wsrc = d ? wd2 : wd1;
        float wv = wsrc[(o * C0 + c) * 9 + k];
        _Float16 hi = (_Float16)wv;
        float rr = wv - (float)hi;
        wdhi[t] = __builtin_bit_cast(u16, hi);
        wdlo[t] = f2h(rr);
    }
    if (t < 4 * C0 * C1) {
        int m = t / (C0 * C1), i = t % (C0 * C1);
        const float* s = (m == 0) ? s1c0 : (m == 1) ? s1h0 : (m == 2) ? s2c0 : s2h0;
        w0h[t] = f2h(s[i]);
    }
    if (t < 4 * C0 * C0) {
        int m = t / (C0 * C0), i = t % (C0 * C0);
        const float* s = (m == 0) ? s1c1 : (m == 1) ? s1h1 : (m == 2) ? s2c1 : s2h1;
        w1h[t] = f2h(s[i]);
    }
}

// ---------------------------------------------------------------------------
// Offset conv: 3x3, 128 -> 18 (f32, round-1 proven)
__global__ __launch_bounds__(256) void k_conv_off(
    const float* __restrict__ x0, const float* __restrict__ wofft,
    const float* __restrict__ boff, float* __restrict__ off)
{
    int bx = blockIdx.x;
    int b  = bx / TPB;
    int p0 = (bx % TPB) * PT;
    int tid = threadIdx.x;
    int p   = tid & 63;
    int cq  = __builtin_amdgcn_readfirstlane(tid >> 6);
    int pos = p0 + p;
    int h = pos / W_, w = pos % W_;

    float acc[18];
#pragma unroll
    for (int o = 0; o < 18; ++o) acc[o] = 0.f;

    for (int cc = 0; cc < 32; ++cc) {
        int c = cq * 32 + cc;
        const float* xb = x0 + ((size_t)(b * C0 + c)) * HW;
        float v[9];
#pragma unroll
        for (int t = 0; t < 9; ++t) {
            int dy = t / 3 - 1, dx = t % 3 - 1;
            int hy = h + dy, wx = w + dx;
            bool ok = (hy >= 0) & (hy < H_) & (wx >= 0) & (wx < W_);
            v[t] = ok ? xb[hy * W_ + wx] : 0.f;
        }
        const float* wr = wofft + c * 162;
#pragma unroll
        for (int o = 0; o < 18; ++o)
#pragma unroll
            for (int t = 0; t < 9; ++t)
                acc[o] = fmaf(wr[o * 9 + t], v[t], acc[o]);
    }

    __shared__ float red[4][18][PT];
#pragma unroll
    for (int o = 0; o < 18; ++o) red[cq][o][p] = acc[o];
    __syncthreads();
    for (int idx = tid; idx < 18 * PT; idx += 256) {
        int o = idx / PT, pp = idx % PT;
        float s = red[0][o][pp] + red[1][o][pp] + red[2][o][pp] + red[3][o][pp]
                + boff[o];
        off[((size_t)(b * 18 + o)) * HW + p0 + pp] = s;
    }
}

// ---------------------------------------------------------------------------
// Fused SFT via MFMA (round-11 version; proven absmax 0.0156)
template <int XSRC>
__global__ __launch_bounds__(512, 6) void k_sft_mma(
    const float* __restrict__ xf,     // XSRC==0
    const float* __restrict__ xT,     // XSRC==1
    const float* __restrict__ x1,
    const u16* __restrict__ w0s, const u16* __restrict__ w0h,   // [128 hid][32 ch]
    const u16* __restrict__ w1s, const u16* __restrict__ w1h,   // [128 out][128 hid]
    const float* __restrict__ b0s, const float* __restrict__ b0h,
    const float* __restrict__ b1s, const float* __restrict__ b1h,
    float* __restrict__ outT)         // [B,HW,128]
{
    __shared__ __align__(16) u16 x1t[64 * 32];
    __shared__ __align__(16) u16 hidt[2][64 * 128];

    int bx = blockIdx.x, b = bx / TPB, p0 = (bx % TPB) * PT;
    int tid = threadIdx.x, l = tid & 63;
    int w = __builtin_amdgcn_readfirstlane(tid >> 6);
    f32x4 zz = {0.f, 0.f, 0.f, 0.f};

    for (int i = tid; i < C1 * PT; i += 512) {
        int ch = i >> 6, pos = i & 63;
        float v = x1[((size_t)(b * C1 + ch)) * HW + p0 + pos];
        x1t[pos * 32 + (ch ^ ((pos & 3) << 3))] = f2h(v);
    }
    __syncthreads();

    {   // hidden GEMM (K=32)
        int mt = w & 3, br = w >> 2;
        int pos = mt * 16 + (l & 15);
        int koff = (l >> 4) * 8;
        f16x8 a = *(const f16x8*)&x1t[pos * 32 + (koff ^ ((pos & 3) << 3))];
        const u16* w0 = br ? w0h : w0s;
        const float* bb = br ? b0h : b0s;
        u16* hrow = hidt[br];
#pragma unroll
        for (int nt = 0; nt < 8; ++nt) {
            int n = nt * 16 + (l & 15);
            f16x8 bfr = *(const f16x8*)&w0[n * 32 + koff];
            f32x4 h = __builtin_amdgcn_mfma_f32_16x16x32_f16(a, bfr, zz, 0, 0, 0);
            float bv = bb[n];
#pragma unroll
            for (int r = 0; r < 4; ++r) {
                float hv = h[r] + bv;
                hv = hv > 0.f ? hv : 0.1f * hv;
                int prow = mt * 16 + (l >> 4) * 4 + r;
                hrow[prow * 128 + (n ^ ((prow & 7) << 3))] = f2h(hv);
            }
        }
    }
    __syncthreads();

    f32x4 accS[4], accH[4];
#pragma unroll
    for (int nt = 0; nt < 4; ++nt) { accS[nt] = zz; accH[nt] = zz; }
    int mt = w & 3, nh = w >> 2;
    int pos = mt * 16 + (l & 15);
#pragma unroll
    for (int ks = 0; ks < 4; ++ks) {
        int kb = ks * 32 + (l >> 4) * 8;
        f16x8 aS = *(const f16x8*)&hidt[0][pos * 128 + (kb ^ ((pos & 7) << 3))];
        f16x8 aH = *(const f16x8*)&hidt[1][pos * 128 + (kb ^ ((pos & 7) << 3))];
#pragma unroll
        for (int nt = 0; nt < 4; ++nt) {
            int n = nh * 64 + nt * 16 + (l & 15);
            f16x8 bS = *(const f16x8*)&w1s[n * 128 + kb];
            f16x8 bH = *(const f16x8*)&w1h[n * 128 + kb];
            accS[nt] = __builtin_amdgcn_mfma_f32_16x16x32_f16(aS, bS, accS[nt], 0, 0, 0);
            accH[nt] = __builtin_amdgcn_mfma_f32_16x16x32_f16(aH, bH, accH[nt], 0, 0, 0);
        }
    }

#pragma unroll
    for (int nt = 0; nt < 4; ++nt) {
        int n = nh * 64 + nt * 16 + (l & 15);
        float scb = b1s[n], shb = b1h[n];
        float xv[4];
        if (XSRC == 0) {
            const float* xp = xf + ((size_t)(b * C0 + n)) * HW + p0 + mt * 16 + (l >> 4) * 4;
            f32x4 x4 = *(const f32x4*)xp;
#pragma unroll
            for (int r = 0; r < 4; ++r) xv[r] = x4[r];
        } else {
#pragma unroll
            for (int r = 0; r < 4; ++r)
                xv[r] = xT[((size_t)(b * HW + p0 + mt * 16 + (l >> 4) * 4 + r)) * C0 + n];
        }
#pragma unroll
        for (int r = 0; r < 4; ++r) {
            float scale = accS[nt][r] + scb + 1.f;
            float shift = accH[nt][r] + shb;
            outT[((size_t)(b * HW + p0 + mt * 16 + (l >> 4) * 4 + r)) * C0 + n]
                = xv[r] * scale + shift;
        }
    }
}

// ---------------------------------------------------------------------------
// Deformable conv 3x3, split-f16 3-term via 32x32x16 MFMA, v7:
//  - raw lgkm-only barriers (NO vmcnt drain in-loop) — d9 discipline
//  - A single-buffered; B staged per K-half (all 128 out rows)
//  - gathers (2x4-pos chunks) + weight loads issued ~1 phase ahead, pinned
//  - LDS 80,896 B -> 2 blocks/CU
// MODE 0: ReLU -> f32 [B,HW,128].  MODE 1: + bias + x0 -> f32 [B,128,HW].
template <int MODE>
__global__ __launch_bounds__(512, 4) void k_deform10(
    const float* __restrict__ srcT,  // [B,HW,128] f32
    const float* __restrict__ off,   // [B,18,HW]
    const u16* __restrict__ whi,     // [9][128 o][128 c] f16 hi
    const u16* __restrict__ wlo,     // [9][128 o][128 c] f16 lo
    const float* __restrict__ bias,
    const float* __restrict__ x0,
    float* __restrict__ outF,        // MODE 1
    float* __restrict__ outT)        // MODE 0
{
    constexpr int SA = 136;          // A row stride (u16): 272 B, 16B-aligned
    constexpr int SB = 72;           // B row stride (u16): 144 B, 16B-aligned
    __shared__ __align__(16) u16   a_buf[2][64 * SA];   // hi/lo  34,816 B
    __shared__ __align__(16) u16   b_buf[2][128 * SB];  // hi/lo  36,864 B
    __shared__ __align__(16) u16   cidx[9 * 64 * 4];    //         4,608 B
    __shared__ __align__(16) float cwt[9 * 64 * 2];     //         4,608 B

    int bx = blockIdx.x;
    bx = (bx & 7) * (NTILE / 8) + (bx >> 3);            // XCD swizzle
    int b = bx / TPB, p0 = (bx % TPB) * PT;
    int tid = threadIdx.x, l = tid & 63;
    int w = __builtin_amdgcn_readfirstlane(tid >> 6);
    int mh = w & 1, ng = w >> 1;                        // 2 pos-halves x 4 out-quarters
    int lr = l & 31, ksel = l >> 5;                     // fragment row / k-segment

    // Phase 0: coords for all 9 taps (computed once)
    for (int e = tid; e < 9 * 64; e += 512) {
        int k = e >> 6, pp = e & 63;
        int pos = p0 + pp, h = pos / W_, wc = pos % W_;
        float dy = off[((size_t)(b * 18 + 2 * k)) * HW + pos];
        float dx = off[((size_t)(b * 18 + 2 * k + 1)) * HW + pos];
        float py = dy + (float)(h + k / 3 - 1);
        float px = dx + (float)(wc + k % 3 - 1);
        float yf = floorf(py), xf = floorf(px);
        int y0 = (int)yf, x0i = (int)xf;
        cwt[e * 2]     = py - yf;
        cwt[e * 2 + 1] = px - xf;
        int iy0 = min(max(y0, 0), H_ - 1),     iy1 = min(max(y0 + 1, 0), H_ - 1);
        int ix0 = min(max(x0i, 0), W_ - 1),    ix1 = min(max(x0i + 1, 0), W_ - 1);
        bool vy0 = (y0 >= 0) & (y0 < H_),      vy1 = (y0 + 1 >= 0) & (y0 + 1 < H_);
        bool vx0 = (x0i >= 0) & (x0i < W_),    vx1 = (x0i + 1 >= 0) & (x0i + 1 < W_);
        cidx[e * 4 + 0] = (u16)(iy0 * W_ + ix0) | ((vy0 & vx0) ? 0x8000 : 0);
        cidx[e * 4 + 1] = (u16)(iy0 * W_ + ix1) | ((vy0 & vx1) ? 0x8000 : 0);
        cidx[e * 4 + 2] = (u16)(iy1 * W_ + ix0) | ((vy1 & vx0) ? 0x8000 : 0);
        cidx[e * 4 + 3] = (u16)(iy1 * W_ + ix1) | ((vy1 & vx1) ? 0x8000 : 0);
    }
    __syncthreads();

    f32x16 acc;
#pragma unroll
    for (int i = 0; i < 16; ++i) acc[i] = 0.f;

    const float* lbase = srcT + (size_t)b * HW * C0 + 2 * l;
    int wrow = tid >> 2, wseg = tid & 3;                // B staging: row, 32B seg

    f32x2 gv1[4][4], gv2[4][4];                         // in-flight A corners
    u32x4 wbh[2], wbl[2];                               // in-flight B weights

#define ISSUE_G(DST, KK, IOFF)                                                \
    {                                                                         \
        int ek = (KK) * 64 + w * 8 + (IOFF);                                  \
        _Pragma("unroll")                                                     \
        for (int i = 0; i < 4; ++i) {                                         \
            int e = ek + i;                                                   \
            u32 c01 = *(const u32*)&cidx[e * 4];                              \
            u32 c23 = *(const u32*)&cidx[e * 4 + 2];                          \
            DST[i][0] = *(const f32x2*)(lbase + (size_t)(c01 & 0x3fffu) * C0);\
            DST[i][1] = *(const f32x2*)(lbase + (size_t)((c01 >> 16) & 0x3fffu) * C0); \
            DST[i][2] = *(const f32x2*)(lbase + (size_t)(c23 & 0x3fffu) * C0);\
            DST[i][3] = *(const f32x2*)(lbase + (size_t)((c23 >> 16) & 0x3fffu) * C0); \
        }                                                                     \
    }

#define COMMIT_CH(SRC, KK, IOFF)                                              \
    {                                                                         \
        int ek = (KK) * 64 + w * 8 + (IOFF);                                  \
        _Pragma("unroll")                                                     \
        for (int i = 0; i < 4; ++i) {                                         \
            int e = ek + i, pp = w * 8 + (IOFF) + i;                          \
            u32 c01 = *(const u32*)&cidx[e * 4];                              \
            u32 c23 = *(const u32*)&cidx[e * 4 + 2];                          \
            float wy = cwt[e * 2], wx = cwt[e * 2 + 1];                       \
            float aa  = wy * wx;                                              \
            float w11 = (c23 & 0x80000000u) ? aa : 0.f;                       \
            float w10 = (c23 & 0x8000u) ? (wy - aa) : 0.f;                    \
            float w01 = (c01 & 0x80000000u) ? (wx - aa) : 0.f;                \
            float w00 = (c01 & 0x8000u) ? (1.f - wy - wx + aa) : 0.f;         \
            float s0 = SRC[i][0][0] * w00 + SRC[i][1][0] * w01                \
                     + SRC[i][2][0] * w10 + SRC[i][3][0] * w11;               \
            float s1 = SRC[i][0][1] * w00 + SRC[i][1][1] * w01                \
                     + SRC[i][2][1] * w10 + SRC[i][3][1] * w11;               \
            _Float16 h0 = (_Float16)s0, h1 = (_Float16)s1;                    \
            float r0 = s0 - (float)h0, r1 = s1 - (float)h1;                   \
            u32 hv = (u32)__builtin_bit_cast(u16, h0)                         \
                   | ((u32)__builtin_bit_cast(u16, h1) << 16);                \
            u32 lv = (u32)f2h(r0) | ((u32)f2h(r1) << 16);                     \
            *(u32*)&a_buf[0][pp * SA + 2 * l] = hv;                           \
            *(u32*)&a_buf[1][pp * SA + 2 * l] = lv;                           \
        }                                                                     \
    }

#define ISSUE_W(KK, KH)                                                       \
    {                                                                         \
        const u16* sh = whi + (size_t)(KK) * 16384 + wrow * 128 + (KH) * 64 + wseg * 16; \
        const u16* sl = wlo + (size_t)(KK) * 16384 + wrow * 128 + (KH) * 64 + wseg * 16; \
        wbh[0] = *(const u32x4*)&sh[0];  wbh[1] = *(const u32x4*)&sh[8];      \
        wbl[0] = *(const u32x4*)&sl[0];  wbl[1] = *(const u32x4*)&sl[8];      \
    }

#define WRITE_B()                                                             \
    {                                                                         \
        *(u32x4*)&b_buf[0][wrow * SB + wseg * 16]     = wbh[0];               \
        *(u32x4*)&b_buf[0][wrow * SB + wseg * 16 + 8] = wbh[1];               \
        *(u32x4*)&b_buf[1][wrow * SB + wseg * 16]     = wbl[0];               \
        *(u32x4*)&b_buf[1][wrow * SB + wseg * 16 + 8] = wbl[1];               \
    }

#define MFMA_PH(KH)                                                           \
    {                                                                         \
        _Pragma("unroll")                                                     \
        for (int ks = 0; ks < 4; ++ks) {                                      \
            int kA = (KH) * 64 + ks * 16 + ksel * 8;                          \
            int kB = ks * 16 + ksel * 8;                                      \
            f16x8 ah = *(const f16x8*)&a_buf[0][(mh * 32 + lr) * SA + kA];    \
            f16x8 al = *(const f16x8*)&a_buf[1][(mh * 32 + lr) * SA + kA];    \
            f16x8 bh = *(const f16x8*)&b_buf[0][(ng * 32 + lr) * SB + kB];    \
            f16x8 bl = *(const f16x8*)&b_buf[1][(ng * 32 + lr) * SB + kB];    \
            acc = __builtin_amdgcn_mfma_f32_32x32x16_f16(ah, bh, acc, 0, 0, 0); \
            acc = __builtin_amdgcn_mfma_f32_32x32x16_f16(al, bh, acc, 0, 0, 0); \
            acc = __builtin_amdgcn_mfma_f32_32x32x16_f16(ah, bl, acc, 0, 0, 0); \
        }                                                                     \
    }

#define LGKM_BAR                                                              \
    asm volatile("s_waitcnt lgkmcnt(0)" ::: "memory");                        \
    __builtin_amdgcn_s_barrier();

    // Prologue (latency exposed once)
    ISSUE_G(gv1, 0, 0)
    ISSUE_G(gv2, 0, 4)
    ISSUE_W(0, 0)
    COMMIT_CH(gv1, 0, 0)
    COMMIT_CH(gv2, 0, 4)
    WRITE_B()
    ISSUE_W(0, 1)
    __builtin_amdgcn_sched_barrier(0);
    LGKM_BAR

    for (int k = 0; k < 9; ++k) {
        // ---- phase 0: b_buf = (k, kh0), a_buf = tap k ----
        __builtin_amdgcn_s_setprio(1);
        MFMA_PH(0)
        __builtin_amdgcn_s_setprio(0);
        if (k < 8) ISSUE_G(gv1, k + 1, 0)
        __builtin_amdgcn_sched_barrier(0);
        LGKM_BAR                              // kh0 reads done
        WRITE_B()                             // publish (k, kh1)
        if (k < 8) { ISSUE_W(k + 1, 0) ISSUE_G(gv2, k + 1, 4) }
        __builtin_amdgcn_sched_barrier(0);
        LGKM_BAR                              // kh1 visible
        // ---- phase 1 ----
        __builtin_amdgcn_s_setprio(1);
        MFMA_PH(1)
        __builtin_amdgcn_s_setprio(0);
        LGKM_BAR                              // a + kh1 reads done
        if (k < 8) {
            COMMIT_CH(gv1, k + 1, 0)          // a_buf <- tap k+1
            COMMIT_CH(gv2, k + 1, 4)
            WRITE_B()                         // publish (k+1, kh0)
            ISSUE_W(k + 1, 1)
        }
        __builtin_amdgcn_sched_barrier(0);
        LGKM_BAR                              // a(k+1), b(k+1,kh0) visible
    }
#undef ISSUE_G
#undef COMMIT_CH
#undef ISSUE_W
#undef WRITE_B
#undef MFMA_PH
#undef LGKM_BAR

    // Epilogue.  C/D map (m74/m101): col = l&31, row = (r&3)+8*(r>>2)+4*(l>>5)
    int o = ng * 32 + lr;
    float bv = bias[o];
    if (MODE == 0) {
        __syncthreads();
        float* otile = (float*)&a_buf[0][0];  // [64][132] f32 = 33,792 B
#pragma unroll
        for (int q = 0; q < 4; ++q) {
            int pr = mh * 32 + q * 8 + 4 * ksel;
#pragma unroll
            for (int r = 0; r < 4; ++r) {
                float v = acc[q * 4 + r] + bv;
                v = v > 0.f ? v : 0.f;
                otile[(pr + r) * 132 + o] = v;
            }
        }
        __syncthreads();
        float* dst = outT + ((size_t)(b * HW + p0)) * C0;
        for (int i = tid; i < 2048; i += 512) {
            int row = i >> 5, c = i & 31;
            *(f32x4*)&dst[row * 128 + c * 4] = *(const f32x4*)&otile[row * 132 + c * 4];
        }
    } else {
#pragma unroll
        for (int q = 0; q < 4; ++q) {
            int pr = mh * 32 + q * 8 + 4 * ksel;
            size_t base_o = ((size_t)(b * C0 + o)) * HW + p0 + pr;
            f32x4 x4 = *(const f32x4*)(x0 + base_o);
            f32x4 ov;
#pragma unroll
            for (int r = 0; r < 4; ++r) ov[r] = acc[q * 4 + r] + bv + x4[r];
            *(f32x4*)(outF + base_o) = ov;
        }
    }
}

// ---------------------------------------------------------------------------
// Workspace layout (bytes)
constexpr size_t WB_OFF   = 0;            // f32 [B,18,HW]        2,654,208
constexpr size_t WB_WOFFT = 2654208;      // f32 [128][162]          82,944
constexpr size_t WB_W0H   = 2737152;      // f16 [4][128][32]        32,768
constexpr size_t WB_W1H   = 2769920;      // f16 [4][128][128]      131,072
constexpr size_t WB_WDHI  = 2900992;      // f16 [2][9][128][128] 1,179,648
constexpr size_t WB_WDLO  = 4080640;      // f16 [2][9][128][128] 1,179,648
constexpr size_t WB_TA    = 5260288;      // f32 [B,HW,128]      18,874,368
constexpr size_t WB_TB    = 24134656;     // f32 [B,HW,128]      18,874,368
// total 43,009,024 B

extern "C" void kernel_launch(void* const* d_in, const int* in_sizes, int n_in,
                              void* d_out, int out_size, void* d_ws, size_t ws_size,
                              hipStream_t stream)
{
    const float* x0      = (const float*)d_in[0];
    const float* x1      = (const float*)d_in[1];
    const float* w_off   = (const float*)d_in[2];
    const float* b_off   = (const float*)d_in[3];
    const float* s1_sc0w = (const float*)d_in[4];
    const float* s1_sc0b = (const float*)d_in[5];
    const float* s1_sc1w = (const float*)d_in[6];
    const float* s1_sc1b = (const float*)d_in[7];
    const float* s1_sh0w = (const float*)d_in[8];
    const float* s1_sh0b = (const float*)d_in[9];
    const float* s1_sh1w = (const float*)d_in[10];
    const float* s1_sh1b = (const float*)d_in[11];
    const float* w_d1    = (const float*)d_in[12];
    const float* b_d1    = (const float*)d_in[13];
    const float* s2_sc0w = (const float*)d_in[14];
    const float* s2_sc0b = (const float*)d_in[15];
    const float* s2_sc1w = (const float*)d_in[16];
    const float* s2_sc1b = (const float*)d_in[17];
    const float* s2_sh0w = (const float*)d_in[18];
    const float* s2_sh0b = (const float*)d_in[19];
    const float* s2_sh1w = (const float*)d_in[20];
    const float* s2_sh1b = (const float*)d_in[21];
    const float* w_d2    = (const float*)d_in[22];
    const float* b_d2    = (const float*)d_in[23];

    char* wsb = (char*)d_ws;
    float* off   = (float*)(wsb + WB_OFF);
    float* wofft = (float*)(wsb + WB_WOFFT);
    u16*   w0h   = (u16*)(wsb + WB_W0H);
    u16*   w1h   = (u16*)(wsb + WB_W1H);
    u16*   wdhi  = (u16*)(wsb + WB_WDHI);
    u16*   wdlo  = (u16*)(wsb + WB_WDLO);
    float* TA    = (float*)(wsb + WB_TA);
    float* TB    = (float*)(wsb + WB_TB);

    k_prep<<<1152, 256, 0, stream>>>(w_off, w_d1, w_d2,
                                     s1_sc0w, s1_sh0w, s2_sc0w, s2_sh0w,
                                     s1_sc1w, s1_sh1w, s2_sc1w, s2_sh1w,
                                     wofft, wdhi, wdlo, w0h, w1h);
    k_conv_off<<<NTILE, 256, 0, stream>>>(x0, wofft, b_off, off);
    // SFT1: x = x0 (channel-major) -> TA (position-major)
    k_sft_mma<0><<<NTILE, 512, 0, stream>>>(x0, nullptr, x1,
                                            w0h, w0h + 4096,
                                            w1h, w1h + 16384,
                                            s1_sc0b, s1_sh0b, s1_sc1b, s1_sh1b, TA);
    // dconv1: gather TA -> relu -> TB (position-major)
    k_deform10<0><<<NTILE, 512, 0, stream>>>(TA, off, wdhi, wdlo, b_d1,
                                             nullptr, nullptr, TB);
    // SFT2: x = TB (position-major) -> TA (position-major)
    k_sft_mma<1><<<NTILE, 512, 0, stream>>>(nullptr, TB, x1,
                                            w0h + 8192, w0h + 12288,
                                            w1h + 32768, w1h + 49152,
                                            s2_sc0b, s2_sh0b, s2_sc1b, s2_sh1b, TA);
    // dconv2: gather TA -> +bias +x0 -> d_out (channel-major)
    k_deform10<1><<<NTILE, 512, 0, stream>>>(TA, off, wdhi + 9 * 16384, wdlo + 9 * 16384,
                                             b_d2, x0, (float*)d_out, nullptr);
}